// Round 3
// baseline (869.972 us; speedup 1.0000x reference)
//
#include <hip/hip_runtime.h>

// Problem constants
#define N_NODES 2048
#define N_EDGES 65536
#define BATCH   4
#define PPIX    4096   // H*W
#define STEPS   4

typedef __attribute__((ext_vector_type(4))) float f32x4;
typedef __attribute__((ext_vector_type(8))) short s16x8;

__device__ __forceinline__ unsigned short f2bf(float f) {
    unsigned u = __float_as_uint(f);
    unsigned r = u + 0x7fffu + ((u >> 16) & 1u);
    return (unsigned short)(r >> 16);
}
__device__ __forceinline__ float bf2f(unsigned short h) {
    return __uint_as_float(((unsigned)h) << 16);
}

// ---------------- sort machinery: counting-sort edges by tgt, nodes by batch ----
__global__ __launch_bounds__(256) void k_hist(const int* __restrict__ ei,
                                              const int* __restrict__ batch_ix,
                                              int* __restrict__ hist,   // 2048 bins (tgt)
                                              int* __restrict__ bcnt) { // 4 bins (batch)
    int i = blockIdx.x * 256 + threadIdx.x;
    if (i < N_EDGES) atomicAdd(&hist[ei[N_EDGES + i]], 1);
    if (i < N_NODES) atomicAdd(&bcnt[batch_ix[i]], 1);
}

__global__ __launch_bounds__(256) void k_scan(const int* __restrict__ hist,
                                              const int* __restrict__ bcnt,
                                              int* __restrict__ cursor,  // 2048: exclusive offsets (consumed by scatter)
                                              int* __restrict__ boff,    // 4: node batch offsets (persist)
                                              int* __restrict__ bcur) {  // 4: scatter cursor for nodes
    __shared__ int tls[256];
    const int t = threadIdx.x;
    int loc[8];
    int s = 0;
#pragma unroll
    for (int j = 0; j < 8; j++) { loc[j] = s; s += hist[t * 8 + j]; }
    tls[t] = s;
    __syncthreads();
    for (int off = 1; off < 256; off <<= 1) {
        int v = (t >= off) ? tls[t - off] : 0;
        __syncthreads();
        tls[t] += v;
        __syncthreads();
    }
    int base = (t > 0) ? tls[t - 1] : 0;
#pragma unroll
    for (int j = 0; j < 8; j++) cursor[t * 8 + j] = base + loc[j];
    if (t == 0) {
        int b = 0;
        for (int i = 0; i < 4; i++) { boff[i] = b; bcur[i] = b; b += bcnt[i]; }
    }
}

__global__ __launch_bounds__(256) void k_scatter(const int* __restrict__ ei,
                                                 const int* __restrict__ batch_ix,
                                                 int* __restrict__ cursor, int* __restrict__ bcur,
                                                 int* __restrict__ perm, int* __restrict__ nperm) {
    int i = blockIdx.x * 256 + threadIdx.x;
    if (i < N_EDGES) {
        int pos = atomicAdd(&cursor[ei[N_EDGES + i]], 1);
        perm[pos] = i;
    }
    if (i < N_NODES) {
        int pos = atomicAdd(&bcur[batch_ix[i]], 1);
        nperm[pos] = i;
    }
}

// ---------------- weight conversion (fp32 -> bf16; mn_w zero-padded K 272->288; ec_w1 added)
__global__ void k_wconv(const float* __restrict__ w1, const float* __restrict__ w2,
                        const float* __restrict__ w3, const float* __restrict__ ec1,
                        unsigned short* __restrict__ o1, unsigned short* __restrict__ o2,
                        unsigned short* __restrict__ o3, unsigned short* __restrict__ o4) {
    int i = blockIdx.x * 256 + threadIdx.x;
    if (i < 256 * 416) o1[i] = f2bf(w1[i]);
    if (i < 128 * 256) o2[i] = f2bf(w2[i]);
    if (i < 128 * 288) {
        int r = i / 288, c = i - r * 288;
        o3[i] = (c < 272) ? f2bf(w3[r * 272 + c]) : (unsigned short)0;
    }
    if (i < 64 * 128) o4[i] = f2bf(ec1[i]);
}

// ---------------- node encoder: relu(x @ ne_w.T + ne_b) -> (2048,128) fp32
__global__ __launch_bounds__(128) void k_node_enc(const float* __restrict__ x,
                                                  const float* __restrict__ w,
                                                  const float* __restrict__ b,
                                                  float* __restrict__ out) {
    __shared__ float xs[256];
    const int n = blockIdx.x;
    for (int i = threadIdx.x; i < 256; i += 128) xs[i] = x[n * 256 + i];
    __syncthreads();
    const int d = threadIdx.x;
    const float* wr = w + d * 256;
    float acc = b[d];
#pragma unroll 8
    for (int c = 0; c < 256; c++) acc += xs[c] * wr[c];
    out[n * 128 + d] = fmaxf(acc, 0.f);
}

// ---------------- edge encoder (writes ef in SORTED slot order)
__global__ __launch_bounds__(256) void k_edge_enc(const float* __restrict__ ea,
                                                  const float* __restrict__ w,
                                                  const float* __restrict__ b,
                                                  const int* __restrict__ perm,
                                                  unsigned short* __restrict__ ef) {
    __shared__ float ws[128 * 64];
    __shared__ float bs[128];
    for (int i = threadIdx.x; i < 128 * 64; i += 256) ws[i] = w[i];
    if (threadIdx.x < 128) bs[threadIdx.x] = b[threadIdx.x];
    __syncthreads();
    const int slot = blockIdx.x * 256 + threadIdx.x;
    const int e = perm[slot];
    float xr[64];
#pragma unroll
    for (int c = 0; c < 64; c++) xr[c] = ea[(size_t)e * 64 + c];
    for (int d = 0; d < 128; d++) {
        float acc = bs[d];
        const float* wr = &ws[d * 64];
#pragma unroll
        for (int c = 0; c < 64; c++) acc += xr[c] * wr[c];
        ef[(size_t)slot * 128 + d] = f2bf(fmaxf(acc, 0.f));
    }
}

// ---------------- queries/values: einsum('oc,bcp->bop') + bias
__global__ __launch_bounds__(256) void k_qv(const float* __restrict__ fm,
                                            const float* __restrict__ qw, const float* __restrict__ qb,
                                            const float* __restrict__ vw, const float* __restrict__ vb,
                                            float* __restrict__ q, float* __restrict__ v) {
    __shared__ float fs[32][256];
    const int b = blockIdx.x >> 4;
    const int pt = blockIdx.x & 15;
    for (int i = threadIdx.x; i < 32 * 256; i += 256) {
        int c = i >> 8, p = i & 255;
        fs[c][p] = fm[(size_t)b * 32 * PPIX + (size_t)c * PPIX + pt * 256 + p];
    }
    __syncthreads();
    const int p = threadIdx.x;
    for (int o = 0; o < 16; o++) {
        float qa = qb[o], va = vb[o];
#pragma unroll
        for (int c = 0; c < 32; c++) {
            float f = fs[c][p];
            qa += qw[o * 32 + c] * f;
            va += vw[o * 32 + c] * f;
        }
        size_t oidx = ((size_t)b * 16 + o) * PPIX + pt * 256 + p;
        q[oidx] = qa;
        v[oidx] = va;
    }
}

// ---------------- attention: 4 nodes/block (same batch), online softmax, q/v read once
__global__ __launch_bounds__(256) void k_attn(const float* __restrict__ nf,
                                              const float* __restrict__ qbuf,
                                              const float* __restrict__ vbuf,
                                              const float* __restrict__ key_w,
                                              const float* __restrict__ key_b,
                                              const int* __restrict__ nperm,
                                              const int* __restrict__ boff,
                                              const int* __restrict__ bcnt,
                                              unsigned short* __restrict__ nf_bf) {
    const int b = blockIdx.x >> 9;       // grid = 4 * 512
    const int chunk = blockIdx.x & 511;
    const int cnt = bcnt[b];
    if (chunk * 4 >= cnt) return;
    const int base = boff[b] + chunk * 4;
    const int nvalid = min(4, cnt - chunk * 4);
    const int t = threadIdx.x;

    __shared__ int nid[4];
    __shared__ float xs[4][128];
    __shared__ float ks[4][16];
    __shared__ float pbuf[4][4][18];   // [wave][node][m, ws, vacc16]

    if (t < 4) nid[t] = nperm[base + ((t < nvalid) ? t : 0)];
    __syncthreads();
    for (int i2 = t; i2 < 4 * 128; i2 += 256) {
        int i = i2 >> 7, d = i2 & 127;
        xs[i][d] = nf[(size_t)nid[i] * 128 + d];
    }
    __syncthreads();
    if (t < 64) {
        int i = t >> 4, a = t & 15;
        const float* wr = key_w + a * 128;
        float acc = key_b[a];
#pragma unroll 8
        for (int c = 0; c < 128; c++) acc += xs[i][c] * wr[c];
        ks[i][a] = acc;
    }
    __syncthreads();

    const float* q = qbuf + (size_t)b * 16 * PPIX;
    const float* v = vbuf + (size_t)b * 16 * PPIX;

    float m[4], wsm[4], vacc[4][16];
#pragma unroll
    for (int i = 0; i < 4; i++) {
        m[i] = -1e30f; wsm[i] = 0.f;
#pragma unroll
        for (int a = 0; a < 16; a++) vacc[i][a] = 0.f;
    }

    for (int ch = 0; ch < 16; ch++) {
        int p = ch * 256 + t;
        float qv[16], vv[16];
#pragma unroll
        for (int a = 0; a < 16; a++) qv[a] = q[a * PPIX + p];
#pragma unroll
        for (int a = 0; a < 16; a++) vv[a] = v[a * PPIX + p];
#pragma unroll
        for (int i = 0; i < 4; i++) {
            float s = 0.f;
#pragma unroll
            for (int a = 0; a < 16; a++) s += ks[i][a] * qv[a];
            if (s > m[i]) {
                float sc = __expf(m[i] - s);
                wsm[i] *= sc;
#pragma unroll
                for (int a = 0; a < 16; a++) vacc[i][a] *= sc;
                m[i] = s;
            }
            float w = __expf(s - m[i]);
            wsm[i] += w;
#pragma unroll
            for (int a = 0; a < 16; a++) vacc[i][a] += w * vv[a];
        }
    }

    // wave-level merge of online-softmax partials
    for (int off = 1; off < 64; off <<= 1) {
#pragma unroll
        for (int i = 0; i < 4; i++) {
            float mo = __shfl_xor(m[i], off);
            float wo = __shfl_xor(wsm[i], off);
            float mn = fmaxf(m[i], mo);
            float se = __expf(m[i] - mn), so = __expf(mo - mn);
            wsm[i] = wsm[i] * se + wo * so;
#pragma unroll
            for (int a = 0; a < 16; a++) {
                float vo = __shfl_xor(vacc[i][a], off);
                vacc[i][a] = vacc[i][a] * se + vo * so;
            }
            m[i] = mn;
        }
    }
    const int wv = t >> 6;
    if ((t & 63) == 0) {
#pragma unroll
        for (int i = 0; i < 4; i++) {
            pbuf[wv][i][0] = m[i];
            pbuf[wv][i][1] = wsm[i];
#pragma unroll
            for (int a = 0; a < 16; a++) pbuf[wv][i][2 + a] = vacc[i][a];
        }
    }
    __syncthreads();
    // cross-wave merge + write res
    if (t < 64) {
        int i = t >> 4, a = t & 15;
        float mg = fmaxf(fmaxf(pbuf[0][i][0], pbuf[1][i][0]), fmaxf(pbuf[2][i][0], pbuf[3][i][0]));
        float num = 0.f, den = 0.f;
#pragma unroll
        for (int w = 0; w < 4; w++) {
            float f = __expf(pbuf[w][i][0] - mg);
            num += pbuf[w][i][2 + a] * f;
            den += pbuf[w][i][1] * f;
        }
        if (i < nvalid) nf_bf[(size_t)nid[i] * 144 + 128 + a] = f2bf(num / den);
    }
    // pack x part
    for (int i2 = t; i2 < 4 * 128; i2 += 256) {
        int i = i2 >> 7, d = i2 & 127;
        if (i < nvalid) nf_bf[(size_t)nid[i] * 144 + d] = f2bf(xs[i][d]);
    }
}

// ---------------- fused 3-layer edge MLP + segment-reduced message scatter
// tile = 32 SORTED edges, 256 threads (4 waves), waves split the N dimension.
__global__ __launch_bounds__(256) void k_mlp(const unsigned short* __restrict__ nf_bf,
                                             unsigned short* __restrict__ ef_buf,
                                             const unsigned short* __restrict__ w1b,
                                             const unsigned short* __restrict__ w2b,
                                             const unsigned short* __restrict__ w3b,
                                             const float* __restrict__ me_b1,
                                             const float* __restrict__ me_b2,
                                             const float* __restrict__ mn_b,
                                             const int* __restrict__ ei,
                                             const int* __restrict__ perm,
                                             float* __restrict__ node_acc) {
    __shared__ __attribute__((aligned(16))) unsigned short catA[32 * 424]; // [x_i 0:144 | x_j 144:288 | ef 288:416 | pad]
    __shared__ __attribute__((aligned(16))) unsigned short out1[32 * 264]; // also reused as msg f32[32][128]
    __shared__ int tgt_s[32];
    __shared__ int src_s[32];
    float* msg = (float*)out1;
    const int tid = threadIdx.x;
    const int e0 = blockIdx.x * 32;
    const int* srcI = ei;
    const int* tgtI = ei + N_EDGES;
    if (tid < 32) {
        int eg = perm[e0 + tid];
        tgt_s[tid] = tgtI[eg];
        src_s[tid] = srcI[eg];
    }
    __syncthreads();
    // gather staging: 52 x 16B chunks per edge
    for (int c = tid; c < 32 * 52; c += 256) {
        int e = c / 52;
        int r = c - e * 52;
        const unsigned short* sp;
        int dcol;
        if (r < 18)      { sp = nf_bf + (size_t)tgt_s[e] * 144 + r * 8;        dcol = r * 8; }
        else if (r < 36) { sp = nf_bf + (size_t)src_s[e] * 144 + (r - 18) * 8; dcol = 144 + (r - 18) * 8; }
        else             { sp = ef_buf + (size_t)(e0 + e) * 128 + (r - 36) * 8; dcol = 288 + (r - 36) * 8; }
        *(s16x8*)&catA[e * 424 + dcol] = *(const s16x8*)sp;
    }
    __syncthreads();

    const int lane = tid & 63;
    const int wid = tid >> 6;       // 0..3 : N-slice owner
    const int lr = lane & 15;
    const int lk = lane >> 4;
    const f32x4 z4 = {0.f, 0.f, 0.f, 0.f};

    // ---- layer 1: (32 x 416) @ (416 x 256) -> out1
    f32x4 acc[2][4];
    for (int mt = 0; mt < 2; mt++)
        for (int nt = 0; nt < 4; nt++) acc[mt][nt] = z4;
    for (int kc = 0; kc < 13; kc++) {
        s16x8 a0 = *(const s16x8*)&catA[(0 + lr) * 424 + kc * 32 + lk * 8];
        s16x8 a1 = *(const s16x8*)&catA[(16 + lr) * 424 + kc * 32 + lk * 8];
#pragma unroll
        for (int nt = 0; nt < 4; nt++) {
            int nn = wid * 64 + nt * 16 + lr;
            s16x8 b = *(const s16x8*)&w1b[(size_t)nn * 416 + kc * 32 + lk * 8];
            acc[0][nt] = __builtin_amdgcn_mfma_f32_16x16x32_bf16(a0, b, acc[0][nt], 0, 0, 0);
            acc[1][nt] = __builtin_amdgcn_mfma_f32_16x16x32_bf16(a1, b, acc[1][nt], 0, 0, 0);
        }
    }
#pragma unroll
    for (int nt = 0; nt < 4; nt++) {
        int nn = wid * 64 + nt * 16 + lr;
        float bias = me_b1[nn];
#pragma unroll
        for (int mt = 0; mt < 2; mt++)
#pragma unroll
            for (int r = 0; r < 4; r++) {
                int m = mt * 16 + lk * 4 + r;
                out1[m * 264 + nn] = f2bf(fmaxf(acc[mt][nt][r] + bias, 0.f));
            }
    }
    __syncthreads();

    // ---- layer 2: (32 x 256) @ (256 x 128) -> ef_new (into catA[.,144:272] and global sorted slot)
    f32x4 acc2[2][2];
    for (int mt = 0; mt < 2; mt++)
        for (int nt = 0; nt < 2; nt++) acc2[mt][nt] = z4;
    for (int kc = 0; kc < 8; kc++) {
        s16x8 a0 = *(const s16x8*)&out1[(0 + lr) * 264 + kc * 32 + lk * 8];
        s16x8 a1 = *(const s16x8*)&out1[(16 + lr) * 264 + kc * 32 + lk * 8];
#pragma unroll
        for (int nt = 0; nt < 2; nt++) {
            int nn = wid * 32 + nt * 16 + lr;
            s16x8 b = *(const s16x8*)&w2b[(size_t)nn * 256 + kc * 32 + lk * 8];
            acc2[0][nt] = __builtin_amdgcn_mfma_f32_16x16x32_bf16(a0, b, acc2[0][nt], 0, 0, 0);
            acc2[1][nt] = __builtin_amdgcn_mfma_f32_16x16x32_bf16(a1, b, acc2[1][nt], 0, 0, 0);
        }
    }
    __syncthreads();   // out1 reads done before msg overlay later; also catA writes ordered
#pragma unroll
    for (int nt = 0; nt < 2; nt++) {
        int nn = wid * 32 + nt * 16 + lr;
        float bias = me_b2[nn];
#pragma unroll
        for (int mt = 0; mt < 2; mt++)
#pragma unroll
            for (int r = 0; r < 4; r++) {
                int m = mt * 16 + lk * 4 + r;
                unsigned short bb = f2bf(fmaxf(acc2[mt][nt][r] + bias, 0.f));
                catA[m * 424 + 144 + nn] = bb;
                ef_buf[(size_t)(e0 + m) * 128 + nn] = bb;
            }
    }
    __syncthreads();

    // ---- layer 3: (32 x 288) @ (288 x 128) -> msg (LDS), then segment-reduce by tgt
    f32x4 acc3[2][2];
    for (int mt = 0; mt < 2; mt++)
        for (int nt = 0; nt < 2; nt++) acc3[mt][nt] = z4;
    for (int kc = 0; kc < 9; kc++) {
        s16x8 a0 = *(const s16x8*)&catA[(0 + lr) * 424 + kc * 32 + lk * 8];
        s16x8 a1 = *(const s16x8*)&catA[(16 + lr) * 424 + kc * 32 + lk * 8];
#pragma unroll
        for (int nt = 0; nt < 2; nt++) {
            int nn = wid * 32 + nt * 16 + lr;
            s16x8 b = *(const s16x8*)&w3b[(size_t)nn * 288 + kc * 32 + lk * 8];
            acc3[0][nt] = __builtin_amdgcn_mfma_f32_16x16x32_bf16(a0, b, acc3[0][nt], 0, 0, 0);
            acc3[1][nt] = __builtin_amdgcn_mfma_f32_16x16x32_bf16(a1, b, acc3[1][nt], 0, 0, 0);
        }
    }
#pragma unroll
    for (int nt = 0; nt < 2; nt++) {
        int nn = wid * 32 + nt * 16 + lr;
        float bias = mn_b[nn];
#pragma unroll
        for (int mt = 0; mt < 2; mt++)
#pragma unroll
            for (int r = 0; r < 4; r++) {
                int m = mt * 16 + lk * 4 + r;
                msg[m * 128 + nn] = fmaxf(acc3[mt][nt][r] + bias, 0.f);
            }
    }
    __syncthreads();
    // segment-reduce: edges sorted by tgt -> few atomics per col
    if (tid < 128) {
        const int c = tid;
        float run = msg[0 * 128 + c];
        int prev = tgt_s[0];
        for (int r = 1; r < 32; r++) {
            int tg = tgt_s[r];
            float val = msg[r * 128 + c];
            if (tg != prev) {
                atomicAdd(&node_acc[(size_t)prev * 128 + c], run);
                run = val;
                prev = tg;
            } else {
                run += val;
            }
        }
        atomicAdd(&node_acc[(size_t)prev * 128 + c], run);
    }
}

// ---------------- edge head (MFMA): pe + fp32 edge_features output (unsorts via perm)
__global__ __launch_bounds__(256) void k_edge_head(const unsigned short* __restrict__ ef,
                                                   const unsigned short* __restrict__ w1b,
                                                   const float* __restrict__ b1,
                                                   const float* __restrict__ w2,
                                                   const float* __restrict__ b2,
                                                   const int* __restrict__ perm,
                                                   float* __restrict__ pe,
                                                   float* __restrict__ ef_out) {
    __shared__ __attribute__((aligned(16))) unsigned short efs[32][136];
    __shared__ float h_s[32][68];
    __shared__ int ep_s[32];
    const int tid = threadIdx.x;
    const int e0 = blockIdx.x * 32;
    if (tid < 32) ep_s[tid] = perm[e0 + tid];
    __syncthreads();
    // stage 32x128 bf16 tile + write fp32 ef_out (at original edge index)
    for (int c = tid; c < 32 * 16; c += 256) {
        int e = c >> 4, r = c & 15;
        s16x8 v = *(const s16x8*)&ef[(size_t)(e0 + e) * 128 + r * 8];
        *(s16x8*)&efs[e][r * 8] = v;
        float4 lo, hi;
        lo.x = bf2f((unsigned short)v[0]); lo.y = bf2f((unsigned short)v[1]);
        lo.z = bf2f((unsigned short)v[2]); lo.w = bf2f((unsigned short)v[3]);
        hi.x = bf2f((unsigned short)v[4]); hi.y = bf2f((unsigned short)v[5]);
        hi.z = bf2f((unsigned short)v[6]); hi.w = bf2f((unsigned short)v[7]);
        size_t ob = (size_t)ep_s[e] * 128 + r * 8;
        *(float4*)&ef_out[ob] = lo;
        *(float4*)&ef_out[ob + 4] = hi;
    }
    __syncthreads();
    const int lane = tid & 63;
    const int wid = tid >> 6;   // owns h block wid*16
    const int lr = lane & 15;
    const int lk = lane >> 4;
    const f32x4 z4 = {0.f, 0.f, 0.f, 0.f};
    f32x4 acc0 = z4, acc1 = z4;
    for (int kc = 0; kc < 4; kc++) {
        s16x8 a0 = *(const s16x8*)&efs[lr][kc * 32 + lk * 8];
        s16x8 a1 = *(const s16x8*)&efs[16 + lr][kc * 32 + lk * 8];
        s16x8 b = *(const s16x8*)&w1b[(size_t)(wid * 16 + lr) * 128 + kc * 32 + lk * 8];
        acc0 = __builtin_amdgcn_mfma_f32_16x16x32_bf16(a0, b, acc0, 0, 0, 0);
        acc1 = __builtin_amdgcn_mfma_f32_16x16x32_bf16(a1, b, acc1, 0, 0, 0);
    }
    {
        int h = wid * 16 + lr;
        float bias = b1[h];
#pragma unroll
        for (int r = 0; r < 4; r++) {
            h_s[lk * 4 + r][h]      = fmaxf(acc0[r] + bias, 0.f);
            h_s[16 + lk * 4 + r][h] = fmaxf(acc1[r] + bias, 0.f);
        }
    }
    __syncthreads();
    if (tid < 32) {
        float a = b2[0];
#pragma unroll 8
        for (int h = 0; h < 64; h++) a += w2[h] * h_s[tid][h];
        pe[ep_s[tid]] = a;
    }
}

// ---------------- fused node heads: pn, pc, nf_out. One wave per node.
__global__ __launch_bounds__(64) void k_node_heads(const float* __restrict__ nf,
                                                   const float* __restrict__ nc_w1, const float* __restrict__ nc_b1,
                                                   const float* __restrict__ nc_w2, const float* __restrict__ nc_b2,
                                                   const float* __restrict__ cl_w1, const float* __restrict__ cl_b1,
                                                   const float* __restrict__ cl_w2, const float* __restrict__ cl_b2,
                                                   float* __restrict__ pn, float* __restrict__ pc,
                                                   float* __restrict__ nf_out) {
    __shared__ float xs[128];
    __shared__ float hr2[64];
    const int n = blockIdx.x;
    const int t = threadIdx.x;
    float2 xv = *(const float2*)&nf[(size_t)n * 128 + t * 2];
    xs[t * 2] = xv.x;
    xs[t * 2 + 1] = xv.y;
    *(float2*)&nf_out[(size_t)n * 128 + t * 2] = xv;
    __syncthreads();
    float a1 = nc_b1[t], a2 = cl_b1[t];
#pragma unroll 8
    for (int d4 = 0; d4 < 32; d4++) {
        float4 w1v = *(const float4*)&nc_w1[(size_t)t * 128 + d4 * 4];
        float4 w2v = *(const float4*)&cl_w1[(size_t)t * 128 + d4 * 4];
        float x0 = xs[d4 * 4], x1 = xs[d4 * 4 + 1], x2 = xs[d4 * 4 + 2], x3 = xs[d4 * 4 + 3];
        a1 += x0 * w1v.x + x1 * w1v.y + x2 * w1v.z + x3 * w1v.w;
        a2 += x0 * w2v.x + x1 * w2v.y + x2 * w2v.z + x3 * w2v.w;
    }
    float h1 = fmaxf(a1, 0.f);
    hr2[t] = fmaxf(a2, 0.f);
    float p = nc_w2[t] * h1;
#pragma unroll
    for (int off = 32; off > 0; off >>= 1) p += __shfl_down(p, off);
    if (t == 0) pn[n] = p + nc_b2[0];
    __syncthreads();
    if (t < 17) {
        float a = cl_b2[t];
#pragma unroll 8
        for (int h = 0; h < 64; h++) a += cl_w2[t * 64 + h] * hr2[h];
        pc[(size_t)n * 17 + t] = a;
    }
}

extern "C" void kernel_launch(void* const* d_in, const int* in_sizes, int n_in,
                              void* d_out, int out_size, void* d_ws, size_t ws_size,
                              hipStream_t stream) {
    const float* x         = (const float*)d_in[0];
    const float* edge_attr = (const float*)d_in[1];
    const int*   edge_idx  = (const int*)d_in[2];
    const float* fmaps     = (const float*)d_in[3];
    const int*   batch_ix  = (const int*)d_in[4];
    const float* ne_w  = (const float*)d_in[5];
    const float* ne_b  = (const float*)d_in[6];
    const float* ee_w  = (const float*)d_in[7];
    const float* ee_b  = (const float*)d_in[8];
    const float* me_w1 = (const float*)d_in[9];
    const float* me_b1 = (const float*)d_in[10];
    const float* me_w2 = (const float*)d_in[11];
    const float* me_b2 = (const float*)d_in[12];
    const float* mn_w  = (const float*)d_in[13];
    const float* mn_b  = (const float*)d_in[14];
    const float* key_w = (const float*)d_in[15];
    const float* key_b = (const float*)d_in[16];
    const float* q_w   = (const float*)d_in[17];
    const float* q_b   = (const float*)d_in[18];
    const float* v_w   = (const float*)d_in[19];
    const float* v_b   = (const float*)d_in[20];
    const float* ec_w1 = (const float*)d_in[21];
    const float* ec_b1 = (const float*)d_in[22];
    const float* ec_w2 = (const float*)d_in[23];
    const float* ec_b2 = (const float*)d_in[24];
    const float* nc_w1 = (const float*)d_in[25];
    const float* nc_b1 = (const float*)d_in[26];
    const float* nc_w2 = (const float*)d_in[27];
    const float* nc_b2 = (const float*)d_in[28];
    const float* cl_w1 = (const float*)d_in[29];
    const float* cl_b1 = (const float*)d_in[30];
    const float* cl_w2 = (const float*)d_in[31];
    const float* cl_b2 = (const float*)d_in[32];

    char* wsp = (char*)d_ws;
    size_t off = 0;
    auto alloc = [&](size_t bytes) -> void* {
        void* p = wsp + off;
        off += (bytes + 255) & ~(size_t)255;
        return p;
    };
    float* q_buf = (float*)alloc((size_t)BATCH * 16 * PPIX * sizeof(float));
    float* v_buf = (float*)alloc((size_t)BATCH * 16 * PPIX * sizeof(float));
    float* nfA   = (float*)alloc((size_t)N_NODES * 128 * sizeof(float));
    float* nfB   = (float*)alloc((size_t)N_NODES * 128 * sizeof(float));
    unsigned short* nf_bf  = (unsigned short*)alloc((size_t)N_NODES * 144 * 2);
    unsigned short* ef_buf = (unsigned short*)alloc((size_t)N_EDGES * 128 * 2);
    unsigned short* w1b = (unsigned short*)alloc(256 * 416 * 2);
    unsigned short* w2b = (unsigned short*)alloc(128 * 256 * 2);
    unsigned short* w3b = (unsigned short*)alloc(128 * 288 * 2);
    unsigned short* w4b = (unsigned short*)alloc(64 * 128 * 2);
    int* hist   = (int*)alloc((2048 + 4) * sizeof(int));   // hist + bcnt (memset together)
    int* bcnt   = hist + 2048;
    int* cursor = (int*)alloc(2048 * sizeof(int));
    int* boff   = (int*)alloc(4 * sizeof(int));
    int* bcur   = (int*)alloc(4 * sizeof(int));
    int* perm   = (int*)alloc((size_t)N_EDGES * sizeof(int));
    int* nperm  = (int*)alloc((size_t)N_NODES * sizeof(int));

    float* pe_out = (float*)d_out;
    float* pn_out = pe_out + N_EDGES;
    float* pc_out = pn_out + N_NODES;
    float* nf_out = pc_out + (size_t)N_NODES * 17;
    float* ef_out = nf_out + (size_t)N_NODES * 128;

    // ---- sort edges by tgt, nodes by batch
    hipMemsetAsync(hist, 0, (2048 + 4) * sizeof(int), stream);
    k_hist<<<N_EDGES / 256, 256, 0, stream>>>(edge_idx, batch_ix, hist, bcnt);
    k_scan<<<1, 256, 0, stream>>>(hist, bcnt, cursor, boff, bcur);
    k_scatter<<<N_EDGES / 256, 256, 0, stream>>>(edge_idx, batch_ix, cursor, bcur, perm, nperm);

    k_wconv<<<416, 256, 0, stream>>>(me_w1, me_w2, mn_w, ec_w1, w1b, w2b, w3b, w4b);
    k_node_enc<<<N_NODES, 128, 0, stream>>>(x, ne_w, ne_b, nfA);
    k_qv<<<64, 256, 0, stream>>>(fmaps, q_w, q_b, v_w, v_b, q_buf, v_buf);
    k_edge_enc<<<N_EDGES / 256, 256, 0, stream>>>(edge_attr, ee_w, ee_b, perm, ef_buf);

    float* cur = nfA;
    float* nxt = nfB;
    for (int step = 0; step < STEPS; step++) {
        k_attn<<<BATCH * 512, 256, 0, stream>>>(cur, q_buf, v_buf, key_w, key_b,
                                                nperm, boff, bcnt, nf_bf);
        hipMemsetAsync(nxt, 0, (size_t)N_NODES * 128 * sizeof(float), stream);
        k_mlp<<<N_EDGES / 32, 256, 0, stream>>>(nf_bf, ef_buf, w1b, w2b, w3b,
                                                me_b1, me_b2, mn_b, edge_idx, perm, nxt);
        float* tmp = cur; cur = nxt; nxt = tmp;
    }

    k_edge_head<<<N_EDGES / 32, 256, 0, stream>>>(ef_buf, w4b, ec_b1, ec_w2, ec_b2, perm, pe_out, ef_out);
    k_node_heads<<<N_NODES, 64, 0, stream>>>(cur, nc_w1, nc_b1, nc_w2, nc_b2,
                                             cl_w1, cl_b1, cl_w2, cl_b2, pn_out, pc_out, nf_out);
}

// Round 4
// 797.269 us; speedup vs baseline: 1.0912x; 1.0912x over previous
//
#include <hip/hip_runtime.h>

// Problem constants
#define N_NODES 2048
#define N_EDGES 65536
#define BATCH   4
#define PPIX    4096   // H*W
#define STEPS   4

typedef __attribute__((ext_vector_type(4))) float f32x4;
typedef __attribute__((ext_vector_type(8))) short s16x8;

__device__ __forceinline__ unsigned short f2bf(float f) {
    unsigned u = __float_as_uint(f);
    unsigned r = u + 0x7fffu + ((u >> 16) & 1u);
    return (unsigned short)(r >> 16);
}
__device__ __forceinline__ float bf2f(unsigned short h) {
    return __uint_as_float(((unsigned)h) << 16);
}

// ---------------- sort machinery: counting-sort edges by tgt, nodes by batch ----
__global__ __launch_bounds__(256) void k_hist(const int* __restrict__ ei,
                                              const int* __restrict__ batch_ix,
                                              int* __restrict__ hist,   // 2048 bins (tgt)
                                              int* __restrict__ bcnt) { // 4 bins (batch)
    int i = blockIdx.x * 256 + threadIdx.x;
    if (i < N_EDGES) atomicAdd(&hist[ei[N_EDGES + i]], 1);
    if (i < N_NODES) atomicAdd(&bcnt[batch_ix[i]], 1);
}

__global__ __launch_bounds__(256) void k_scan(const int* __restrict__ hist,
                                              const int* __restrict__ bcnt,
                                              int* __restrict__ cursor,  // 2048: exclusive offsets (consumed by scatter)
                                              int* __restrict__ boff,    // 4: node batch offsets (persist)
                                              int* __restrict__ bcur) {  // 4: scatter cursor for nodes
    __shared__ int tls[256];
    const int t = threadIdx.x;
    int loc[8];
    int s = 0;
#pragma unroll
    for (int j = 0; j < 8; j++) { loc[j] = s; s += hist[t * 8 + j]; }
    tls[t] = s;
    __syncthreads();
    for (int off = 1; off < 256; off <<= 1) {
        int v = (t >= off) ? tls[t - off] : 0;
        __syncthreads();
        tls[t] += v;
        __syncthreads();
    }
    int base = (t > 0) ? tls[t - 1] : 0;
#pragma unroll
    for (int j = 0; j < 8; j++) cursor[t * 8 + j] = base + loc[j];
    if (t == 0) {
        int b = 0;
        for (int i = 0; i < 4; i++) { boff[i] = b; bcur[i] = b; b += bcnt[i]; }
    }
}

__global__ __launch_bounds__(256) void k_scatter(const int* __restrict__ ei,
                                                 const int* __restrict__ batch_ix,
                                                 int* __restrict__ cursor, int* __restrict__ bcur,
                                                 int* __restrict__ perm, int* __restrict__ nperm) {
    int i = blockIdx.x * 256 + threadIdx.x;
    if (i < N_EDGES) {
        int pos = atomicAdd(&cursor[ei[N_EDGES + i]], 1);
        perm[pos] = i;
    }
    if (i < N_NODES) {
        int pos = atomicAdd(&bcur[batch_ix[i]], 1);
        nperm[pos] = i;
    }
}

// ---------------- weight conversion (fp32 -> bf16; mn_w zero-padded K 272->288; ec_w1 added)
__global__ void k_wconv(const float* __restrict__ w1, const float* __restrict__ w2,
                        const float* __restrict__ w3, const float* __restrict__ ec1,
                        unsigned short* __restrict__ o1, unsigned short* __restrict__ o2,
                        unsigned short* __restrict__ o3, unsigned short* __restrict__ o4) {
    int i = blockIdx.x * 256 + threadIdx.x;
    if (i < 256 * 416) o1[i] = f2bf(w1[i]);
    if (i < 128 * 256) o2[i] = f2bf(w2[i]);
    if (i < 128 * 288) {
        int r = i / 288, c = i - r * 288;
        o3[i] = (c < 272) ? f2bf(w3[r * 272 + c]) : (unsigned short)0;
    }
    if (i < 64 * 128) o4[i] = f2bf(ec1[i]);
}

// ---------------- node encoder: relu(x @ ne_w.T + ne_b) -> (2048,128) fp32
__global__ __launch_bounds__(128) void k_node_enc(const float* __restrict__ x,
                                                  const float* __restrict__ w,
                                                  const float* __restrict__ b,
                                                  float* __restrict__ out) {
    __shared__ float xs[256];
    const int n = blockIdx.x;
    for (int i = threadIdx.x; i < 256; i += 128) xs[i] = x[n * 256 + i];
    __syncthreads();
    const int d = threadIdx.x;
    const float* wr = w + d * 256;
    float acc = b[d];
#pragma unroll 8
    for (int c = 0; c < 256; c++) acc += xs[c] * wr[c];
    out[n * 128 + d] = fmaxf(acc, 0.f);
}

// ---------------- edge encoder (writes ef in SORTED slot order)
__global__ __launch_bounds__(256) void k_edge_enc(const float* __restrict__ ea,
                                                  const float* __restrict__ w,
                                                  const float* __restrict__ b,
                                                  const int* __restrict__ perm,
                                                  unsigned short* __restrict__ ef) {
    __shared__ float ws[128 * 64];
    __shared__ float bs[128];
    for (int i = threadIdx.x; i < 128 * 64; i += 256) ws[i] = w[i];
    if (threadIdx.x < 128) bs[threadIdx.x] = b[threadIdx.x];
    __syncthreads();
    const int slot = blockIdx.x * 256 + threadIdx.x;
    const int e = perm[slot];
    float xr[64];
#pragma unroll
    for (int c = 0; c < 64; c++) xr[c] = ea[(size_t)e * 64 + c];
    for (int d = 0; d < 128; d++) {
        float acc = bs[d];
        const float* wr = &ws[d * 64];
#pragma unroll
        for (int c = 0; c < 64; c++) acc += xr[c] * wr[c];
        ef[(size_t)slot * 128 + d] = f2bf(fmaxf(acc, 0.f));
    }
}

// ---------------- queries/values: einsum('oc,bcp->bop') + bias
__global__ __launch_bounds__(256) void k_qv(const float* __restrict__ fm,
                                            const float* __restrict__ qw, const float* __restrict__ qb,
                                            const float* __restrict__ vw, const float* __restrict__ vb,
                                            float* __restrict__ q, float* __restrict__ v) {
    __shared__ float fs[32][256];
    const int b = blockIdx.x >> 4;
    const int pt = blockIdx.x & 15;
    for (int i = threadIdx.x; i < 32 * 256; i += 256) {
        int c = i >> 8, p = i & 255;
        fs[c][p] = fm[(size_t)b * 32 * PPIX + (size_t)c * PPIX + pt * 256 + p];
    }
    __syncthreads();
    const int p = threadIdx.x;
    for (int o = 0; o < 16; o++) {
        float qa = qb[o], va = vb[o];
#pragma unroll
        for (int c = 0; c < 32; c++) {
            float f = fs[c][p];
            qa += qw[o * 32 + c] * f;
            va += vw[o * 32 + c] * f;
        }
        size_t oidx = ((size_t)b * 16 + o) * PPIX + pt * 256 + p;
        q[oidx] = qa;
        v[oidx] = va;
    }
}

// ---------------- attention: 4 nodes/block (same batch), online softmax, q/v read once.
// Also zeroes the next-step node accumulator rows (replaces a memset dispatch).
__global__ __launch_bounds__(256) void k_attn(const float* __restrict__ nf,
                                              const float* __restrict__ qbuf,
                                              const float* __restrict__ vbuf,
                                              const float* __restrict__ key_w,
                                              const float* __restrict__ key_b,
                                              const int* __restrict__ nperm,
                                              const int* __restrict__ boff,
                                              const int* __restrict__ bcnt,
                                              unsigned short* __restrict__ nf_bf,
                                              float* __restrict__ nxt) {
    const int b = blockIdx.x >> 9;       // grid = 4 * 512
    const int chunk = blockIdx.x & 511;
    const int cnt = bcnt[b];
    if (chunk * 4 >= cnt) return;
    const int base = boff[b] + chunk * 4;
    const int nvalid = min(4, cnt - chunk * 4);
    const int t = threadIdx.x;

    __shared__ int nid[4];
    __shared__ float xs[4][128];
    __shared__ float ks[4][16];
    __shared__ float pbuf[4][4][18];   // [wave][node][m, ws, vacc16]

    if (t < 4) nid[t] = nperm[base + ((t < nvalid) ? t : 0)];
    __syncthreads();
    for (int i2 = t; i2 < 4 * 128; i2 += 256) {
        int i = i2 >> 7, d = i2 & 127;
        xs[i][d] = nf[(size_t)nid[i] * 128 + d];
        if (i < nvalid) nxt[(size_t)nid[i] * 128 + d] = 0.f;   // zero next accumulator
    }
    __syncthreads();
    if (t < 64) {
        int i = t >> 4, a = t & 15;
        const float* wr = key_w + a * 128;
        float acc = key_b[a];
#pragma unroll 8
        for (int c = 0; c < 128; c++) acc += xs[i][c] * wr[c];
        ks[i][a] = acc;
    }
    __syncthreads();

    const float* q = qbuf + (size_t)b * 16 * PPIX;
    const float* v = vbuf + (size_t)b * 16 * PPIX;

    float m[4], wsm[4], vacc[4][16];
#pragma unroll
    for (int i = 0; i < 4; i++) {
        m[i] = -1e30f; wsm[i] = 0.f;
#pragma unroll
        for (int a = 0; a < 16; a++) vacc[i][a] = 0.f;
    }

    for (int ch = 0; ch < 16; ch++) {
        int p = ch * 256 + t;
        float qv[16], vv[16];
#pragma unroll
        for (int a = 0; a < 16; a++) qv[a] = q[a * PPIX + p];
#pragma unroll
        for (int a = 0; a < 16; a++) vv[a] = v[a * PPIX + p];
#pragma unroll
        for (int i = 0; i < 4; i++) {
            float s = 0.f;
#pragma unroll
            for (int a = 0; a < 16; a++) s += ks[i][a] * qv[a];
            if (s > m[i]) {
                float sc = __expf(m[i] - s);
                wsm[i] *= sc;
#pragma unroll
                for (int a = 0; a < 16; a++) vacc[i][a] *= sc;
                m[i] = s;
            }
            float w = __expf(s - m[i]);
            wsm[i] += w;
#pragma unroll
            for (int a = 0; a < 16; a++) vacc[i][a] += w * vv[a];
        }
    }

    // wave-level merge of online-softmax partials
    for (int off = 1; off < 64; off <<= 1) {
#pragma unroll
        for (int i = 0; i < 4; i++) {
            float mo = __shfl_xor(m[i], off);
            float wo = __shfl_xor(wsm[i], off);
            float mn = fmaxf(m[i], mo);
            float se = __expf(m[i] - mn), so = __expf(mo - mn);
            wsm[i] = wsm[i] * se + wo * so;
#pragma unroll
            for (int a = 0; a < 16; a++) {
                float vo = __shfl_xor(vacc[i][a], off);
                vacc[i][a] = vacc[i][a] * se + vo * so;
            }
            m[i] = mn;
        }
    }
    const int wv = t >> 6;
    if ((t & 63) == 0) {
#pragma unroll
        for (int i = 0; i < 4; i++) {
            pbuf[wv][i][0] = m[i];
            pbuf[wv][i][1] = wsm[i];
#pragma unroll
            for (int a = 0; a < 16; a++) pbuf[wv][i][2 + a] = vacc[i][a];
        }
    }
    __syncthreads();
    // cross-wave merge + write res
    if (t < 64) {
        int i = t >> 4, a = t & 15;
        float mg = fmaxf(fmaxf(pbuf[0][i][0], pbuf[1][i][0]), fmaxf(pbuf[2][i][0], pbuf[3][i][0]));
        float num = 0.f, den = 0.f;
#pragma unroll
        for (int w = 0; w < 4; w++) {
            float f = __expf(pbuf[w][i][0] - mg);
            num += pbuf[w][i][2 + a] * f;
            den += pbuf[w][i][1] * f;
        }
        if (i < nvalid) nf_bf[(size_t)nid[i] * 144 + 128 + a] = f2bf(num / den);
    }
    // pack x part
    for (int i2 = t; i2 < 4 * 128; i2 += 256) {
        int i = i2 >> 7, d = i2 & 127;
        if (i < nvalid) nf_bf[(size_t)nid[i] * 144 + d] = f2bf(xs[i][d]);
    }
}

// ---------------- fused 3-layer edge MLP + segment-reduced message scatter
// tile = 32 SORTED edges, 256 threads (4 waves), waves split the N dimension.
// LDS overlay: out1 / ef_new / msg all live in catA cols 144:416 after their
// producers' reads complete (x_j and ef are dead after L1). LDS = 27.4 KB ->
// 4 blocks/CU (VGPR-capped at 16 waves via __launch_bounds__(256,4)).
__global__ __launch_bounds__(256, 4) void k_mlp(const unsigned short* __restrict__ nf_bf,
                                                unsigned short* __restrict__ ef_buf,
                                                const unsigned short* __restrict__ w1b,
                                                const unsigned short* __restrict__ w2b,
                                                const unsigned short* __restrict__ w3b,
                                                const float* __restrict__ me_b1,
                                                const float* __restrict__ me_b2,
                                                const float* __restrict__ mn_b,
                                                const int* __restrict__ ei,
                                                const int* __restrict__ perm,
                                                float* __restrict__ node_acc) {
    __shared__ __attribute__((aligned(16))) unsigned short catA[32 * 424]; // [x_i 0:144 | x_j 144:288 | ef 288:416 | pad]
    __shared__ int tgt_s[32];
    __shared__ int src_s[32];
    const int tid = threadIdx.x;
    const int e0 = blockIdx.x * 32;
    const int* srcI = ei;
    const int* tgtI = ei + N_EDGES;
    if (tid < 32) {
        int eg = perm[e0 + tid];
        tgt_s[tid] = tgtI[eg];
        src_s[tid] = srcI[eg];
    }
    __syncthreads();
    // gather staging: 52 x 16B chunks per edge
    for (int c = tid; c < 32 * 52; c += 256) {
        int e = c / 52;
        int r = c - e * 52;
        const unsigned short* sp;
        int dcol;
        if (r < 18)      { sp = nf_bf + (size_t)tgt_s[e] * 144 + r * 8;        dcol = r * 8; }
        else if (r < 36) { sp = nf_bf + (size_t)src_s[e] * 144 + (r - 18) * 8; dcol = 144 + (r - 18) * 8; }
        else             { sp = ef_buf + (size_t)(e0 + e) * 128 + (r - 36) * 8; dcol = 288 + (r - 36) * 8; }
        *(s16x8*)&catA[e * 424 + dcol] = *(const s16x8*)sp;
    }
    __syncthreads();

    const int lane = tid & 63;
    const int wid = tid >> 6;       // 0..3 : N-slice owner
    const int lr = lane & 15;
    const int lk = lane >> 4;
    const f32x4 z4 = {0.f, 0.f, 0.f, 0.f};

    // ---- layer 1: (32 x 416) @ (416 x 256) -> acc
    f32x4 acc[2][4];
    for (int mt = 0; mt < 2; mt++)
        for (int nt = 0; nt < 4; nt++) acc[mt][nt] = z4;
#pragma unroll 2
    for (int kc = 0; kc < 13; kc++) {
        s16x8 a0 = *(const s16x8*)&catA[(0 + lr) * 424 + kc * 32 + lk * 8];
        s16x8 a1 = *(const s16x8*)&catA[(16 + lr) * 424 + kc * 32 + lk * 8];
#pragma unroll
        for (int nt = 0; nt < 4; nt++) {
            int nn = wid * 64 + nt * 16 + lr;
            s16x8 b = *(const s16x8*)&w1b[(size_t)nn * 416 + kc * 32 + lk * 8];
            acc[0][nt] = __builtin_amdgcn_mfma_f32_16x16x32_bf16(a0, b, acc[0][nt], 0, 0, 0);
            acc[1][nt] = __builtin_amdgcn_mfma_f32_16x16x32_bf16(a1, b, acc[1][nt], 0, 0, 0);
        }
    }
    __syncthreads();   // all L1 reads of catA done -> cols 144:416 now dead
    // write out1 (bf16, 256 cols) into overlay catA cols 144:400
#pragma unroll
    for (int nt = 0; nt < 4; nt++) {
        int nn = wid * 64 + nt * 16 + lr;
        float bias = me_b1[nn];
#pragma unroll
        for (int mt = 0; mt < 2; mt++)
#pragma unroll
            for (int r = 0; r < 4; r++) {
                int m = mt * 16 + lk * 4 + r;
                catA[m * 424 + 144 + nn] = f2bf(fmaxf(acc[mt][nt][r] + bias, 0.f));
            }
    }
    __syncthreads();

    // ---- layer 2: (32 x 256) @ (256 x 128) -> acc2 (regs)
    f32x4 acc2[2][2];
    for (int mt = 0; mt < 2; mt++)
        for (int nt = 0; nt < 2; nt++) acc2[mt][nt] = z4;
#pragma unroll 2
    for (int kc = 0; kc < 8; kc++) {
        s16x8 a0 = *(const s16x8*)&catA[(0 + lr) * 424 + 144 + kc * 32 + lk * 8];
        s16x8 a1 = *(const s16x8*)&catA[(16 + lr) * 424 + 144 + kc * 32 + lk * 8];
#pragma unroll
        for (int nt = 0; nt < 2; nt++) {
            int nn = wid * 32 + nt * 16 + lr;
            s16x8 b = *(const s16x8*)&w2b[(size_t)nn * 256 + kc * 32 + lk * 8];
            acc2[0][nt] = __builtin_amdgcn_mfma_f32_16x16x32_bf16(a0, b, acc2[0][nt], 0, 0, 0);
            acc2[1][nt] = __builtin_amdgcn_mfma_f32_16x16x32_bf16(a1, b, acc2[1][nt], 0, 0, 0);
        }
    }
    __syncthreads();   // all L2 reads of out1 overlay done
    // write ef_new (bf16) into catA cols 144:272 (LDS only; global write deferred to end)
#pragma unroll
    for (int nt = 0; nt < 2; nt++) {
        int nn = wid * 32 + nt * 16 + lr;
        float bias = me_b2[nn];
#pragma unroll
        for (int mt = 0; mt < 2; mt++)
#pragma unroll
            for (int r = 0; r < 4; r++) {
                int m = mt * 16 + lk * 4 + r;
                catA[m * 424 + 144 + nn] = f2bf(fmaxf(acc2[mt][nt][r] + bias, 0.f));
            }
    }
    __syncthreads();

    // ---- layer 3: (32 x 288) @ (288 x 128) -> acc3 (regs). cols 272:288 junk x zero-weights.
    f32x4 acc3[2][2];
    for (int mt = 0; mt < 2; mt++)
        for (int nt = 0; nt < 2; nt++) acc3[mt][nt] = z4;
#pragma unroll 2
    for (int kc = 0; kc < 9; kc++) {
        s16x8 a0 = *(const s16x8*)&catA[(0 + lr) * 424 + kc * 32 + lk * 8];
        s16x8 a1 = *(const s16x8*)&catA[(16 + lr) * 424 + kc * 32 + lk * 8];
#pragma unroll
        for (int nt = 0; nt < 2; nt++) {
            int nn = wid * 32 + nt * 16 + lr;
            s16x8 b = *(const s16x8*)&w3b[(size_t)nn * 288 + kc * 32 + lk * 8];
            acc3[0][nt] = __builtin_amdgcn_mfma_f32_16x16x32_bf16(a0, b, acc3[0][nt], 0, 0, 0);
            acc3[1][nt] = __builtin_amdgcn_mfma_f32_16x16x32_bf16(a1, b, acc3[1][nt], 0, 0, 0);
        }
    }
    __syncthreads();   // all L3 reads of catA done -> overlay free for msg (fp32)
    // msg[m][c] (fp32, 128 cols) at bytes [288:800] of each catA row
#pragma unroll
    for (int nt = 0; nt < 2; nt++) {
        int nn = wid * 32 + nt * 16 + lr;
        float bias = mn_b[nn];
#pragma unroll
        for (int mt = 0; mt < 2; mt++)
#pragma unroll
            for (int r = 0; r < 4; r++) {
                int m = mt * 16 + lk * 4 + r;
                *(float*)&catA[m * 424 + 144 + nn * 2] = fmaxf(acc3[mt][nt][r] + bias, 0.f);
            }
    }
    __syncthreads();
    // segment-reduce: edges sorted by tgt -> few atomics per col
    if (tid < 128) {
        const int c = tid;
        float run = *(const float*)&catA[0 * 424 + 144 + c * 2];
        int prev = tgt_s[0];
        for (int r = 1; r < 32; r++) {
            int tg = tgt_s[r];
            float val = *(const float*)&catA[r * 424 + 144 + c * 2];
            if (tg != prev) {
                atomicAdd(&node_acc[(size_t)prev * 128 + c], run);
                run = val;
                prev = tg;
            } else {
                run += val;
            }
        }
        atomicAdd(&node_acc[(size_t)prev * 128 + c], run);
    }
    // deferred global ef write (from acc2 regs; no barrier after -> no drain stall)
#pragma unroll
    for (int nt = 0; nt < 2; nt++) {
        int nn = wid * 32 + nt * 16 + lr;
        float bias = me_b2[nn];
#pragma unroll
        for (int mt = 0; mt < 2; mt++)
#pragma unroll
            for (int r = 0; r < 4; r++) {
                int m = mt * 16 + lk * 4 + r;
                ef_buf[(size_t)(e0 + m) * 128 + nn] = f2bf(fmaxf(acc2[mt][nt][r] + bias, 0.f));
            }
    }
}

// ---------------- edge head (MFMA): pe + fp32 edge_features output (unsorts via perm)
__global__ __launch_bounds__(256) void k_edge_head(const unsigned short* __restrict__ ef,
                                                   const unsigned short* __restrict__ w1b,
                                                   const float* __restrict__ b1,
                                                   const float* __restrict__ w2,
                                                   const float* __restrict__ b2,
                                                   const int* __restrict__ perm,
                                                   float* __restrict__ pe,
                                                   float* __restrict__ ef_out) {
    __shared__ __attribute__((aligned(16))) unsigned short efs[32][136];
    __shared__ float h_s[32][68];
    __shared__ int ep_s[32];
    const int tid = threadIdx.x;
    const int e0 = blockIdx.x * 32;
    if (tid < 32) ep_s[tid] = perm[e0 + tid];
    __syncthreads();
    // stage 32x128 bf16 tile + write fp32 ef_out (at original edge index)
    for (int c = tid; c < 32 * 16; c += 256) {
        int e = c >> 4, r = c & 15;
        s16x8 v = *(const s16x8*)&ef[(size_t)(e0 + e) * 128 + r * 8];
        *(s16x8*)&efs[e][r * 8] = v;
        float4 lo, hi;
        lo.x = bf2f((unsigned short)v[0]); lo.y = bf2f((unsigned short)v[1]);
        lo.z = bf2f((unsigned short)v[2]); lo.w = bf2f((unsigned short)v[3]);
        hi.x = bf2f((unsigned short)v[4]); hi.y = bf2f((unsigned short)v[5]);
        hi.z = bf2f((unsigned short)v[6]); hi.w = bf2f((unsigned short)v[7]);
        size_t ob = (size_t)ep_s[e] * 128 + r * 8;
        *(float4*)&ef_out[ob] = lo;
        *(float4*)&ef_out[ob + 4] = hi;
    }
    __syncthreads();
    const int lane = tid & 63;
    const int wid = tid >> 6;   // owns h block wid*16
    const int lr = lane & 15;
    const int lk = lane >> 4;
    const f32x4 z4 = {0.f, 0.f, 0.f, 0.f};
    f32x4 acc0 = z4, acc1 = z4;
    for (int kc = 0; kc < 4; kc++) {
        s16x8 a0 = *(const s16x8*)&efs[lr][kc * 32 + lk * 8];
        s16x8 a1 = *(const s16x8*)&efs[16 + lr][kc * 32 + lk * 8];
        s16x8 b = *(const s16x8*)&w1b[(size_t)(wid * 16 + lr) * 128 + kc * 32 + lk * 8];
        acc0 = __builtin_amdgcn_mfma_f32_16x16x32_bf16(a0, b, acc0, 0, 0, 0);
        acc1 = __builtin_amdgcn_mfma_f32_16x16x32_bf16(a1, b, acc1, 0, 0, 0);
    }
    {
        int h = wid * 16 + lr;
        float bias = b1[h];
#pragma unroll
        for (int r = 0; r < 4; r++) {
            h_s[lk * 4 + r][h]      = fmaxf(acc0[r] + bias, 0.f);
            h_s[16 + lk * 4 + r][h] = fmaxf(acc1[r] + bias, 0.f);
        }
    }
    __syncthreads();
    if (tid < 32) {
        float a = b2[0];
#pragma unroll 8
        for (int h = 0; h < 64; h++) a += w2[h] * h_s[tid][h];
        pe[ep_s[tid]] = a;
    }
}

// ---------------- fused node heads: pn, pc, nf_out. One wave per node.
__global__ __launch_bounds__(64) void k_node_heads(const float* __restrict__ nf,
                                                   const float* __restrict__ nc_w1, const float* __restrict__ nc_b1,
                                                   const float* __restrict__ nc_w2, const float* __restrict__ nc_b2,
                                                   const float* __restrict__ cl_w1, const float* __restrict__ cl_b1,
                                                   const float* __restrict__ cl_w2, const float* __restrict__ cl_b2,
                                                   float* __restrict__ pn, float* __restrict__ pc,
                                                   float* __restrict__ nf_out) {
    __shared__ float xs[128];
    __shared__ float hr2[64];
    const int n = blockIdx.x;
    const int t = threadIdx.x;
    float2 xv = *(const float2*)&nf[(size_t)n * 128 + t * 2];
    xs[t * 2] = xv.x;
    xs[t * 2 + 1] = xv.y;
    *(float2*)&nf_out[(size_t)n * 128 + t * 2] = xv;
    __syncthreads();
    float a1 = nc_b1[t], a2 = cl_b1[t];
#pragma unroll 8
    for (int d4 = 0; d4 < 32; d4++) {
        float4 w1v = *(const float4*)&nc_w1[(size_t)t * 128 + d4 * 4];
        float4 w2v = *(const float4*)&cl_w1[(size_t)t * 128 + d4 * 4];
        float x0 = xs[d4 * 4], x1 = xs[d4 * 4 + 1], x2 = xs[d4 * 4 + 2], x3 = xs[d4 * 4 + 3];
        a1 += x0 * w1v.x + x1 * w1v.y + x2 * w1v.z + x3 * w1v.w;
        a2 += x0 * w2v.x + x1 * w2v.y + x2 * w2v.z + x3 * w2v.w;
    }
    float h1 = fmaxf(a1, 0.f);
    hr2[t] = fmaxf(a2, 0.f);
    float p = nc_w2[t] * h1;
#pragma unroll
    for (int off = 32; off > 0; off >>= 1) p += __shfl_down(p, off);
    if (t == 0) pn[n] = p + nc_b2[0];
    __syncthreads();
    if (t < 17) {
        float a = cl_b2[t];
#pragma unroll 8
        for (int h = 0; h < 64; h++) a += cl_w2[t * 64 + h] * hr2[h];
        pc[(size_t)n * 17 + t] = a;
    }
}

extern "C" void kernel_launch(void* const* d_in, const int* in_sizes, int n_in,
                              void* d_out, int out_size, void* d_ws, size_t ws_size,
                              hipStream_t stream) {
    const float* x         = (const float*)d_in[0];
    const float* edge_attr = (const float*)d_in[1];
    const int*   edge_idx  = (const int*)d_in[2];
    const float* fmaps     = (const float*)d_in[3];
    const int*   batch_ix  = (const int*)d_in[4];
    const float* ne_w  = (const float*)d_in[5];
    const float* ne_b  = (const float*)d_in[6];
    const float* ee_w  = (const float*)d_in[7];
    const float* ee_b  = (const float*)d_in[8];
    const float* me_w1 = (const float*)d_in[9];
    const float* me_b1 = (const float*)d_in[10];
    const float* me_w2 = (const float*)d_in[11];
    const float* me_b2 = (const float*)d_in[12];
    const float* mn_w  = (const float*)d_in[13];
    const float* mn_b  = (const float*)d_in[14];
    const float* key_w = (const float*)d_in[15];
    const float* key_b = (const float*)d_in[16];
    const float* q_w   = (const float*)d_in[17];
    const float* q_b   = (const float*)d_in[18];
    const float* v_w   = (const float*)d_in[19];
    const float* v_b   = (const float*)d_in[20];
    const float* ec_w1 = (const float*)d_in[21];
    const float* ec_b1 = (const float*)d_in[22];
    const float* ec_w2 = (const float*)d_in[23];
    const float* ec_b2 = (const float*)d_in[24];
    const float* nc_w1 = (const float*)d_in[25];
    const float* nc_b1 = (const float*)d_in[26];
    const float* nc_w2 = (const float*)d_in[27];
    const float* nc_b2 = (const float*)d_in[28];
    const float* cl_w1 = (const float*)d_in[29];
    const float* cl_b1 = (const float*)d_in[30];
    const float* cl_w2 = (const float*)d_in[31];
    const float* cl_b2 = (const float*)d_in[32];

    char* wsp = (char*)d_ws;
    size_t off = 0;
    auto alloc = [&](size_t bytes) -> void* {
        void* p = wsp + off;
        off += (bytes + 255) & ~(size_t)255;
        return p;
    };
    float* q_buf = (float*)alloc((size_t)BATCH * 16 * PPIX * sizeof(float));
    float* v_buf = (float*)alloc((size_t)BATCH * 16 * PPIX * sizeof(float));
    float* nfA   = (float*)alloc((size_t)N_NODES * 128 * sizeof(float));
    float* nfB   = (float*)alloc((size_t)N_NODES * 128 * sizeof(float));
    unsigned short* nf_bf  = (unsigned short*)alloc((size_t)N_NODES * 144 * 2);
    unsigned short* ef_buf = (unsigned short*)alloc((size_t)N_EDGES * 128 * 2);
    unsigned short* w1b = (unsigned short*)alloc(256 * 416 * 2);
    unsigned short* w2b = (unsigned short*)alloc(128 * 256 * 2);
    unsigned short* w3b = (unsigned short*)alloc(128 * 288 * 2);
    unsigned short* w4b = (unsigned short*)alloc(64 * 128 * 2);
    int* hist   = (int*)alloc((2048 + 4) * sizeof(int));   // hist + bcnt (memset together)
    int* bcnt   = hist + 2048;
    int* cursor = (int*)alloc(2048 * sizeof(int));
    int* boff   = (int*)alloc(4 * sizeof(int));
    int* bcur   = (int*)alloc(4 * sizeof(int));
    int* perm   = (int*)alloc((size_t)N_EDGES * sizeof(int));
    int* nperm  = (int*)alloc((size_t)N_NODES * sizeof(int));

    float* pe_out = (float*)d_out;
    float* pn_out = pe_out + N_EDGES;
    float* pc_out = pn_out + N_NODES;
    float* nf_out = pc_out + (size_t)N_NODES * 17;
    float* ef_out = nf_out + (size_t)N_NODES * 128;

    // ---- sort edges by tgt, nodes by batch
    hipMemsetAsync(hist, 0, (2048 + 4) * sizeof(int), stream);
    k_hist<<<N_EDGES / 256, 256, 0, stream>>>(edge_idx, batch_ix, hist, bcnt);
    k_scan<<<1, 256, 0, stream>>>(hist, bcnt, cursor, boff, bcur);
    k_scatter<<<N_EDGES / 256, 256, 0, stream>>>(edge_idx, batch_ix, cursor, bcur, perm, nperm);

    k_wconv<<<416, 256, 0, stream>>>(me_w1, me_w2, mn_w, ec_w1, w1b, w2b, w3b, w4b);
    k_node_enc<<<N_NODES, 128, 0, stream>>>(x, ne_w, ne_b, nfA);
    k_qv<<<64, 256, 0, stream>>>(fmaps, q_w, q_b, v_w, v_b, q_buf, v_buf);
    k_edge_enc<<<N_EDGES / 256, 256, 0, stream>>>(edge_attr, ee_w, ee_b, perm, ef_buf);

    float* cur = nfA;
    float* nxt = nfB;
    for (int step = 0; step < STEPS; step++) {
        k_attn<<<BATCH * 512, 256, 0, stream>>>(cur, q_buf, v_buf, key_w, key_b,
                                                nperm, boff, bcnt, nf_bf, nxt);
        k_mlp<<<N_EDGES / 32, 256, 0, stream>>>(nf_bf, ef_buf, w1b, w2b, w3b,
                                                me_b1, me_b2, mn_b, edge_idx, perm, nxt);
        float* tmp = cur; cur = nxt; nxt = tmp;
    }

    k_edge_head<<<N_EDGES / 32, 256, 0, stream>>>(ef_buf, w4b, ec_b1, ec_w2, ec_b2, perm, pe_out, ef_out);
    k_node_heads<<<N_NODES, 64, 0, stream>>>(cur, nc_w1, nc_b1, nc_w2, nc_b2,
                                             cl_w1, cl_b1, cl_w2, cl_b2, pn_out, pc_out, nf_out);
}

// Round 5
// 790.408 us; speedup vs baseline: 1.1007x; 1.0087x over previous
//
#include <hip/hip_runtime.h>

// Problem constants
#define N_NODES 2048
#define N_EDGES 65536
#define BATCH   4
#define PPIX    4096   // H*W
#define STEPS   4

typedef __attribute__((ext_vector_type(4))) float f32x4;
typedef __attribute__((ext_vector_type(8))) short s16x8;

__device__ __forceinline__ unsigned short f2bf(float f) {
    unsigned u = __float_as_uint(f);
    unsigned r = u + 0x7fffu + ((u >> 16) & 1u);
    return (unsigned short)(r >> 16);
}
__device__ __forceinline__ float bf2f(unsigned short h) {
    return __uint_as_float(((unsigned)h) << 16);
}

// ---------------- sort machinery: counting-sort edges by tgt, nodes by batch ----
__global__ __launch_bounds__(256) void k_hist(const int* __restrict__ ei,
                                              const int* __restrict__ batch_ix,
                                              int* __restrict__ hist,   // 2048 bins (tgt)
                                              int* __restrict__ bcnt) { // 4 bins (batch)
    int i = blockIdx.x * 256 + threadIdx.x;
    if (i < N_EDGES) atomicAdd(&hist[ei[N_EDGES + i]], 1);
    if (i < N_NODES) atomicAdd(&bcnt[batch_ix[i]], 1);
}

__global__ __launch_bounds__(256) void k_scan(const int* __restrict__ hist,
                                              const int* __restrict__ bcnt,
                                              int* __restrict__ cursor,  // 2048: exclusive offsets (consumed by scatter)
                                              int* __restrict__ boff,    // 4: node batch offsets (persist)
                                              int* __restrict__ bcur) {  // 4: scatter cursor for nodes
    __shared__ int tls[256];
    const int t = threadIdx.x;
    int loc[8];
    int s = 0;
#pragma unroll
    for (int j = 0; j < 8; j++) { loc[j] = s; s += hist[t * 8 + j]; }
    tls[t] = s;
    __syncthreads();
    for (int off = 1; off < 256; off <<= 1) {
        int v = (t >= off) ? tls[t - off] : 0;
        __syncthreads();
        tls[t] += v;
        __syncthreads();
    }
    int base = (t > 0) ? tls[t - 1] : 0;
#pragma unroll
    for (int j = 0; j < 8; j++) cursor[t * 8 + j] = base + loc[j];
    if (t == 0) {
        int b = 0;
        for (int i = 0; i < 4; i++) { boff[i] = b; bcur[i] = b; b += bcnt[i]; }
    }
}

__global__ __launch_bounds__(256) void k_scatter(const int* __restrict__ ei,
                                                 const int* __restrict__ batch_ix,
                                                 int* __restrict__ cursor, int* __restrict__ bcur,
                                                 int* __restrict__ perm, int* __restrict__ nperm) {
    int i = blockIdx.x * 256 + threadIdx.x;
    if (i < N_EDGES) {
        int pos = atomicAdd(&cursor[ei[N_EDGES + i]], 1);
        perm[pos] = i;
    }
    if (i < N_NODES) {
        int pos = atomicAdd(&bcur[batch_ix[i]], 1);
        nperm[pos] = i;
    }
}

// ---------------- weight conversion (fp32 -> bf16; mn_w zero-padded K 272->288; ec_w1 added)
__global__ void k_wconv(const float* __restrict__ w1, const float* __restrict__ w2,
                        const float* __restrict__ w3, const float* __restrict__ ec1,
                        unsigned short* __restrict__ o1, unsigned short* __restrict__ o2,
                        unsigned short* __restrict__ o3, unsigned short* __restrict__ o4) {
    int i = blockIdx.x * 256 + threadIdx.x;
    if (i < 256 * 416) o1[i] = f2bf(w1[i]);
    if (i < 128 * 256) o2[i] = f2bf(w2[i]);
    if (i < 128 * 288) {
        int r = i / 288, c = i - r * 288;
        o3[i] = (c < 272) ? f2bf(w3[r * 272 + c]) : (unsigned short)0;
    }
    if (i < 64 * 128) o4[i] = f2bf(ec1[i]);
}

// ---------------- node encoder: relu(x @ ne_w.T + ne_b) -> (2048,128) fp32
__global__ __launch_bounds__(128) void k_node_enc(const float* __restrict__ x,
                                                  const float* __restrict__ w,
                                                  const float* __restrict__ b,
                                                  float* __restrict__ out) {
    __shared__ float xs[256];
    const int n = blockIdx.x;
    for (int i = threadIdx.x; i < 256; i += 128) xs[i] = x[n * 256 + i];
    __syncthreads();
    const int d = threadIdx.x;
    const float* wr = w + d * 256;
    float acc = b[d];
#pragma unroll 8
    for (int c = 0; c < 256; c++) acc += xs[c] * wr[c];
    out[n * 128 + d] = fmaxf(acc, 0.f);
}

// ---------------- edge encoder (writes ef in SORTED slot order)
__global__ __launch_bounds__(256) void k_edge_enc(const float* __restrict__ ea,
                                                  const float* __restrict__ w,
                                                  const float* __restrict__ b,
                                                  const int* __restrict__ perm,
                                                  unsigned short* __restrict__ ef) {
    __shared__ float ws[128 * 64];
    __shared__ float bs[128];
    for (int i = threadIdx.x; i < 128 * 64; i += 256) ws[i] = w[i];
    if (threadIdx.x < 128) bs[threadIdx.x] = b[threadIdx.x];
    __syncthreads();
    const int slot = blockIdx.x * 256 + threadIdx.x;
    const int e = perm[slot];
    float xr[64];
#pragma unroll
    for (int c = 0; c < 64; c++) xr[c] = ea[(size_t)e * 64 + c];
    for (int d = 0; d < 128; d++) {
        float acc = bs[d];
        const float* wr = &ws[d * 64];
#pragma unroll
        for (int c = 0; c < 64; c++) acc += xr[c] * wr[c];
        ef[(size_t)slot * 128 + d] = f2bf(fmaxf(acc, 0.f));
    }
}

// ---------------- queries/values: einsum('oc,bcp->bop') + bias
__global__ __launch_bounds__(256) void k_qv(const float* __restrict__ fm,
                                            const float* __restrict__ qw, const float* __restrict__ qb,
                                            const float* __restrict__ vw, const float* __restrict__ vb,
                                            float* __restrict__ q, float* __restrict__ v) {
    __shared__ float fs[32][256];
    const int b = blockIdx.x >> 4;
    const int pt = blockIdx.x & 15;
    for (int i = threadIdx.x; i < 32 * 256; i += 256) {
        int c = i >> 8, p = i & 255;
        fs[c][p] = fm[(size_t)b * 32 * PPIX + (size_t)c * PPIX + pt * 256 + p];
    }
    __syncthreads();
    const int p = threadIdx.x;
    for (int o = 0; o < 16; o++) {
        float qa = qb[o], va = vb[o];
#pragma unroll
        for (int c = 0; c < 32; c++) {
            float f = fs[c][p];
            qa += qw[o * 32 + c] * f;
            va += vw[o * 32 + c] * f;
        }
        size_t oidx = ((size_t)b * 16 + o) * PPIX + pt * 256 + p;
        q[oidx] = qa;
        v[oidx] = va;
    }
}

// ---------------- attention: 4 nodes/block (same batch), online softmax, q/v read once.
// Also zeroes the next-step node accumulator rows (replaces a memset dispatch).
__global__ __launch_bounds__(256) void k_attn(const float* __restrict__ nf,
                                              const float* __restrict__ qbuf,
                                              const float* __restrict__ vbuf,
                                              const float* __restrict__ key_w,
                                              const float* __restrict__ key_b,
                                              const int* __restrict__ nperm,
                                              const int* __restrict__ boff,
                                              const int* __restrict__ bcnt,
                                              unsigned short* __restrict__ nf_bf,
                                              float* __restrict__ nxt) {
    const int b = blockIdx.x >> 9;       // grid = 4 * 512
    const int chunk = blockIdx.x & 511;
    const int cnt = bcnt[b];
    if (chunk * 4 >= cnt) return;
    const int base = boff[b] + chunk * 4;
    const int nvalid = min(4, cnt - chunk * 4);
    const int t = threadIdx.x;

    __shared__ int nid[4];
    __shared__ float xs[4][128];
    __shared__ float ks[4][16];
    __shared__ float pbuf[4][4][18];   // [wave][node][m, ws, vacc16]

    if (t < 4) nid[t] = nperm[base + ((t < nvalid) ? t : 0)];
    __syncthreads();
    for (int i2 = t; i2 < 4 * 128; i2 += 256) {
        int i = i2 >> 7, d = i2 & 127;
        xs[i][d] = nf[(size_t)nid[i] * 128 + d];
        if (i < nvalid) nxt[(size_t)nid[i] * 128 + d] = 0.f;   // zero next accumulator
    }
    __syncthreads();
    if (t < 64) {
        int i = t >> 4, a = t & 15;
        const float* wr = key_w + a * 128;
        float acc = key_b[a];
#pragma unroll 8
        for (int c = 0; c < 128; c++) acc += xs[i][c] * wr[c];
        ks[i][a] = acc;
    }
    __syncthreads();

    const float* q = qbuf + (size_t)b * 16 * PPIX;
    const float* v = vbuf + (size_t)b * 16 * PPIX;

    float m[4], wsm[4], vacc[4][16];
#pragma unroll
    for (int i = 0; i < 4; i++) {
        m[i] = -1e30f; wsm[i] = 0.f;
#pragma unroll
        for (int a = 0; a < 16; a++) vacc[i][a] = 0.f;
    }

    for (int ch = 0; ch < 16; ch++) {
        int p = ch * 256 + t;
        float qv[16], vv[16];
#pragma unroll
        for (int a = 0; a < 16; a++) qv[a] = q[a * PPIX + p];
#pragma unroll
        for (int a = 0; a < 16; a++) vv[a] = v[a * PPIX + p];
#pragma unroll
        for (int i = 0; i < 4; i++) {
            float s = 0.f;
#pragma unroll
            for (int a = 0; a < 16; a++) s += ks[i][a] * qv[a];
            if (s > m[i]) {
                float sc = __expf(m[i] - s);
                wsm[i] *= sc;
#pragma unroll
                for (int a = 0; a < 16; a++) vacc[i][a] *= sc;
                m[i] = s;
            }
            float w = __expf(s - m[i]);
            wsm[i] += w;
#pragma unroll
            for (int a = 0; a < 16; a++) vacc[i][a] += w * vv[a];
        }
    }

    // wave-level merge of online-softmax partials
    for (int off = 1; off < 64; off <<= 1) {
#pragma unroll
        for (int i = 0; i < 4; i++) {
            float mo = __shfl_xor(m[i], off);
            float wo = __shfl_xor(wsm[i], off);
            float mn = fmaxf(m[i], mo);
            float se = __expf(m[i] - mn), so = __expf(mo - mn);
            wsm[i] = wsm[i] * se + wo * so;
#pragma unroll
            for (int a = 0; a < 16; a++) {
                float vo = __shfl_xor(vacc[i][a], off);
                vacc[i][a] = vacc[i][a] * se + vo * so;
            }
            m[i] = mn;
        }
    }
    const int wv = t >> 6;
    if ((t & 63) == 0) {
#pragma unroll
        for (int i = 0; i < 4; i++) {
            pbuf[wv][i][0] = m[i];
            pbuf[wv][i][1] = wsm[i];
#pragma unroll
            for (int a = 0; a < 16; a++) pbuf[wv][i][2 + a] = vacc[i][a];
        }
    }
    __syncthreads();
    // cross-wave merge + write res
    if (t < 64) {
        int i = t >> 4, a = t & 15;
        float mg = fmaxf(fmaxf(pbuf[0][i][0], pbuf[1][i][0]), fmaxf(pbuf[2][i][0], pbuf[3][i][0]));
        float num = 0.f, den = 0.f;
#pragma unroll
        for (int w = 0; w < 4; w++) {
            float f = __expf(pbuf[w][i][0] - mg);
            num += pbuf[w][i][2 + a] * f;
            den += pbuf[w][i][1] * f;
        }
        if (i < nvalid) nf_bf[(size_t)nid[i] * 144 + 128 + a] = f2bf(num / den);
    }
    // pack x part
    for (int i2 = t; i2 < 4 * 128; i2 += 256) {
        int i = i2 >> 7, d = i2 & 127;
        if (i < nvalid) nf_bf[(size_t)nid[i] * 144 + d] = f2bf(xs[i][d]);
    }
}

// ---------------- fused 3-layer edge MLP + segment-reduced message scatter
// tile = 64 SORTED edges, 512 threads (8 waves): wave = (m-half wm) x (n-slice wn).
// LDS overlay as before; catA = 64 rows x 424 cols bf16 = 54.3 KB -> 2 blocks/CU
// (16 waves = 50% occ, __launch_bounds__(512,4) caps VGPR at 128).
// Rationale: 32-edge tiles streamed 344 KB of L2 weights per block (704 MB/dispatch);
// 64-edge tiles halve weight traffic per edge and double MFMA per latency chain.
__global__ __launch_bounds__(512, 4) void k_mlp(const unsigned short* __restrict__ nf_bf,
                                                unsigned short* __restrict__ ef_buf,
                                                const unsigned short* __restrict__ w1b,
                                                const unsigned short* __restrict__ w2b,
                                                const unsigned short* __restrict__ w3b,
                                                const float* __restrict__ me_b1,
                                                const float* __restrict__ me_b2,
                                                const float* __restrict__ mn_b,
                                                const int* __restrict__ ei,
                                                const int* __restrict__ perm,
                                                float* __restrict__ node_acc) {
    __shared__ __attribute__((aligned(16))) unsigned short catA[64 * 424]; // [x_i 0:144 | x_j 144:288 | ef 288:416 | pad]
    __shared__ int tgt_s[64];
    __shared__ int src_s[64];
    const int tid = threadIdx.x;
    const int e0 = blockIdx.x * 64;
    const int* srcI = ei;
    const int* tgtI = ei + N_EDGES;
    if (tid < 64) {
        int eg = perm[e0 + tid];
        tgt_s[tid] = tgtI[eg];
        src_s[tid] = srcI[eg];
    }
    __syncthreads();
    // gather staging: 52 x 16B chunks per edge, 64 edges
    for (int c = tid; c < 64 * 52; c += 512) {
        int e = c / 52;
        int r = c - e * 52;
        const unsigned short* sp;
        int dcol;
        if (r < 18)      { sp = nf_bf + (size_t)tgt_s[e] * 144 + r * 8;        dcol = r * 8; }
        else if (r < 36) { sp = nf_bf + (size_t)src_s[e] * 144 + (r - 18) * 8; dcol = 144 + (r - 18) * 8; }
        else             { sp = ef_buf + (size_t)(e0 + e) * 128 + (r - 36) * 8; dcol = 288 + (r - 36) * 8; }
        *(s16x8*)&catA[e * 424 + dcol] = *(const s16x8*)sp;
    }
    __syncthreads();

    const int lane = tid & 63;
    const int wid = tid >> 6;       // 0..7
    const int wm = wid >> 2;        // m-half: rows [wm*32, wm*32+32)
    const int wn = wid & 3;         // n-slice
    const int lr = lane & 15;
    const int lk = lane >> 4;
    const int rbase = wm * 32;
    const f32x4 z4 = {0.f, 0.f, 0.f, 0.f};

    // ---- layer 1: (64 x 416) @ (416 x 256); wave: rows rbase..+32, cols wn*64..+64
    f32x4 acc[2][4];
    for (int mt = 0; mt < 2; mt++)
        for (int nt = 0; nt < 4; nt++) acc[mt][nt] = z4;
#pragma unroll 2
    for (int kc = 0; kc < 13; kc++) {
        s16x8 a0 = *(const s16x8*)&catA[(rbase + lr) * 424 + kc * 32 + lk * 8];
        s16x8 a1 = *(const s16x8*)&catA[(rbase + 16 + lr) * 424 + kc * 32 + lk * 8];
#pragma unroll
        for (int nt = 0; nt < 4; nt++) {
            int nn = wn * 64 + nt * 16 + lr;
            s16x8 b = *(const s16x8*)&w1b[(size_t)nn * 416 + kc * 32 + lk * 8];
            acc[0][nt] = __builtin_amdgcn_mfma_f32_16x16x32_bf16(a0, b, acc[0][nt], 0, 0, 0);
            acc[1][nt] = __builtin_amdgcn_mfma_f32_16x16x32_bf16(a1, b, acc[1][nt], 0, 0, 0);
        }
    }
    __syncthreads();   // all L1 reads of catA done -> cols 144:416 now dead
    // write out1 (bf16, 256 cols) into overlay catA cols 144:400
#pragma unroll
    for (int nt = 0; nt < 4; nt++) {
        int nn = wn * 64 + nt * 16 + lr;
        float bias = me_b1[nn];
#pragma unroll
        for (int mt = 0; mt < 2; mt++)
#pragma unroll
            for (int r = 0; r < 4; r++) {
                int m = rbase + mt * 16 + lk * 4 + r;
                catA[m * 424 + 144 + nn] = f2bf(fmaxf(acc[mt][nt][r] + bias, 0.f));
            }
    }
    __syncthreads();

    // ---- layer 2: (64 x 256) @ (256 x 128) -> acc2 (regs); cols wn*32..+32
    f32x4 acc2[2][2];
    for (int mt = 0; mt < 2; mt++)
        for (int nt = 0; nt < 2; nt++) acc2[mt][nt] = z4;
#pragma unroll 2
    for (int kc = 0; kc < 8; kc++) {
        s16x8 a0 = *(const s16x8*)&catA[(rbase + lr) * 424 + 144 + kc * 32 + lk * 8];
        s16x8 a1 = *(const s16x8*)&catA[(rbase + 16 + lr) * 424 + 144 + kc * 32 + lk * 8];
#pragma unroll
        for (int nt = 0; nt < 2; nt++) {
            int nn = wn * 32 + nt * 16 + lr;
            s16x8 b = *(const s16x8*)&w2b[(size_t)nn * 256 + kc * 32 + lk * 8];
            acc2[0][nt] = __builtin_amdgcn_mfma_f32_16x16x32_bf16(a0, b, acc2[0][nt], 0, 0, 0);
            acc2[1][nt] = __builtin_amdgcn_mfma_f32_16x16x32_bf16(a1, b, acc2[1][nt], 0, 0, 0);
        }
    }
    __syncthreads();   // all L2 reads of out1 overlay done
    // write ef_new (bf16) into catA cols 144:272 (LDS only; global write deferred to end)
#pragma unroll
    for (int nt = 0; nt < 2; nt++) {
        int nn = wn * 32 + nt * 16 + lr;
        float bias = me_b2[nn];
#pragma unroll
        for (int mt = 0; mt < 2; mt++)
#pragma unroll
            for (int r = 0; r < 4; r++) {
                int m = rbase + mt * 16 + lk * 4 + r;
                catA[m * 424 + 144 + nn] = f2bf(fmaxf(acc2[mt][nt][r] + bias, 0.f));
            }
    }
    __syncthreads();

    // ---- layer 3: (64 x 288) @ (288 x 128) -> acc3 (regs). cols 272:288 junk x zero-weights.
    f32x4 acc3[2][2];
    for (int mt = 0; mt < 2; mt++)
        for (int nt = 0; nt < 2; nt++) acc3[mt][nt] = z4;
#pragma unroll 2
    for (int kc = 0; kc < 9; kc++) {
        s16x8 a0 = *(const s16x8*)&catA[(rbase + lr) * 424 + kc * 32 + lk * 8];
        s16x8 a1 = *(const s16x8*)&catA[(rbase + 16 + lr) * 424 + kc * 32 + lk * 8];
#pragma unroll
        for (int nt = 0; nt < 2; nt++) {
            int nn = wn * 32 + nt * 16 + lr;
            s16x8 b = *(const s16x8*)&w3b[(size_t)nn * 288 + kc * 32 + lk * 8];
            acc3[0][nt] = __builtin_amdgcn_mfma_f32_16x16x32_bf16(a0, b, acc3[0][nt], 0, 0, 0);
            acc3[1][nt] = __builtin_amdgcn_mfma_f32_16x16x32_bf16(a1, b, acc3[1][nt], 0, 0, 0);
        }
    }
    __syncthreads();   // all L3 reads of catA done -> overlay free for msg (fp32)
    // msg[m][c] (fp32, 128 cols) at element offset 144 + 2c of each catA row
#pragma unroll
    for (int nt = 0; nt < 2; nt++) {
        int nn = wn * 32 + nt * 16 + lr;
        float bias = mn_b[nn];
#pragma unroll
        for (int mt = 0; mt < 2; mt++)
#pragma unroll
            for (int r = 0; r < 4; r++) {
                int m = rbase + mt * 16 + lk * 4 + r;
                *(float*)&catA[m * 424 + 144 + nn * 2] = fmaxf(acc3[mt][nt][r] + bias, 0.f);
            }
    }
    __syncthreads();
    // segment-reduce: sorted tgt -> runs; 512 threads = 128 cols x 4 row-chunks of 16
    {
        const int c = tid & 127;
        const int r0 = (tid >> 7) * 16;
        float run = *(const float*)&catA[r0 * 424 + 144 + c * 2];
        int prev = tgt_s[r0];
        for (int r = r0 + 1; r < r0 + 16; r++) {
            int tg = tgt_s[r];
            float val = *(const float*)&catA[r * 424 + 144 + c * 2];
            if (tg != prev) {
                atomicAdd(&node_acc[(size_t)prev * 128 + c], run);
                run = val;
                prev = tg;
            } else {
                run += val;
            }
        }
        atomicAdd(&node_acc[(size_t)prev * 128 + c], run);
    }
    // deferred global ef write (from acc2 regs; no barrier after -> no drain stall)
#pragma unroll
    for (int nt = 0; nt < 2; nt++) {
        int nn = wn * 32 + nt * 16 + lr;
        float bias = me_b2[nn];
#pragma unroll
        for (int mt = 0; mt < 2; mt++)
#pragma unroll
            for (int r = 0; r < 4; r++) {
                int m = rbase + mt * 16 + lk * 4 + r;
                ef_buf[(size_t)(e0 + m) * 128 + nn] = f2bf(fmaxf(acc2[mt][nt][r] + bias, 0.f));
            }
    }
}

// ---------------- edge head (MFMA): pe + fp32 edge_features output (unsorts via perm)
__global__ __launch_bounds__(256) void k_edge_head(const unsigned short* __restrict__ ef,
                                                   const unsigned short* __restrict__ w1b,
                                                   const float* __restrict__ b1,
                                                   const float* __restrict__ w2,
                                                   const float* __restrict__ b2,
                                                   const int* __restrict__ perm,
                                                   float* __restrict__ pe,
                                                   float* __restrict__ ef_out) {
    __shared__ __attribute__((aligned(16))) unsigned short efs[32][136];
    __shared__ float h_s[32][68];
    __shared__ int ep_s[32];
    const int tid = threadIdx.x;
    const int e0 = blockIdx.x * 32;
    if (tid < 32) ep_s[tid] = perm[e0 + tid];
    __syncthreads();
    // stage 32x128 bf16 tile + write fp32 ef_out (at original edge index)
    for (int c = tid; c < 32 * 16; c += 256) {
        int e = c >> 4, r = c & 15;
        s16x8 v = *(const s16x8*)&ef[(size_t)(e0 + e) * 128 + r * 8];
        *(s16x8*)&efs[e][r * 8] = v;
        float4 lo, hi;
        lo.x = bf2f((unsigned short)v[0]); lo.y = bf2f((unsigned short)v[1]);
        lo.z = bf2f((unsigned short)v[2]); lo.w = bf2f((unsigned short)v[3]);
        hi.x = bf2f((unsigned short)v[4]); hi.y = bf2f((unsigned short)v[5]);
        hi.z = bf2f((unsigned short)v[6]); hi.w = bf2f((unsigned short)v[7]);
        size_t ob = (size_t)ep_s[e] * 128 + r * 8;
        *(float4*)&ef_out[ob] = lo;
        *(float4*)&ef_out[ob + 4] = hi;
    }
    __syncthreads();
    const int lane = tid & 63;
    const int wid = tid >> 6;   // owns h block wid*16
    const int lr = lane & 15;
    const int lk = lane >> 4;
    const f32x4 z4 = {0.f, 0.f, 0.f, 0.f};
    f32x4 acc0 = z4, acc1 = z4;
    for (int kc = 0; kc < 4; kc++) {
        s16x8 a0 = *(const s16x8*)&efs[lr][kc * 32 + lk * 8];
        s16x8 a1 = *(const s16x8*)&efs[16 + lr][kc * 32 + lk * 8];
        s16x8 b = *(const s16x8*)&w1b[(size_t)(wid * 16 + lr) * 128 + kc * 32 + lk * 8];
        acc0 = __builtin_amdgcn_mfma_f32_16x16x32_bf16(a0, b, acc0, 0, 0, 0);
        acc1 = __builtin_amdgcn_mfma_f32_16x16x32_bf16(a1, b, acc1, 0, 0, 0);
    }
    {
        int h = wid * 16 + lr;
        float bias = b1[h];
#pragma unroll
        for (int r = 0; r < 4; r++) {
            h_s[lk * 4 + r][h]      = fmaxf(acc0[r] + bias, 0.f);
            h_s[16 + lk * 4 + r][h] = fmaxf(acc1[r] + bias, 0.f);
        }
    }
    __syncthreads();
    if (tid < 32) {
        float a = b2[0];
#pragma unroll 8
        for (int h = 0; h < 64; h++) a += w2[h] * h_s[tid][h];
        pe[ep_s[tid]] = a;
    }
}

// ---------------- fused node heads: pn, pc, nf_out. One wave per node.
__global__ __launch_bounds__(64) void k_node_heads(const float* __restrict__ nf,
                                                   const float* __restrict__ nc_w1, const float* __restrict__ nc_b1,
                                                   const float* __restrict__ nc_w2, const float* __restrict__ nc_b2,
                                                   const float* __restrict__ cl_w1, const float* __restrict__ cl_b1,
                                                   const float* __restrict__ cl_w2, const float* __restrict__ cl_b2,
                                                   float* __restrict__ pn, float* __restrict__ pc,
                                                   float* __restrict__ nf_out) {
    __shared__ float xs[128];
    __shared__ float hr2[64];
    const int n = blockIdx.x;
    const int t = threadIdx.x;
    float2 xv = *(const float2*)&nf[(size_t)n * 128 + t * 2];
    xs[t * 2] = xv.x;
    xs[t * 2 + 1] = xv.y;
    *(float2*)&nf_out[(size_t)n * 128 + t * 2] = xv;
    __syncthreads();
    float a1 = nc_b1[t], a2 = cl_b1[t];
#pragma unroll 8
    for (int d4 = 0; d4 < 32; d4++) {
        float4 w1v = *(const float4*)&nc_w1[(size_t)t * 128 + d4 * 4];
        float4 w2v = *(const float4*)&cl_w1[(size_t)t * 128 + d4 * 4];
        float x0 = xs[d4 * 4], x1 = xs[d4 * 4 + 1], x2 = xs[d4 * 4 + 2], x3 = xs[d4 * 4 + 3];
        a1 += x0 * w1v.x + x1 * w1v.y + x2 * w1v.z + x3 * w1v.w;
        a2 += x0 * w2v.x + x1 * w2v.y + x2 * w2v.z + x3 * w2v.w;
    }
    float h1 = fmaxf(a1, 0.f);
    hr2[t] = fmaxf(a2, 0.f);
    float p = nc_w2[t] * h1;
#pragma unroll
    for (int off = 32; off > 0; off >>= 1) p += __shfl_down(p, off);
    if (t == 0) pn[n] = p + nc_b2[0];
    __syncthreads();
    if (t < 17) {
        float a = cl_b2[t];
#pragma unroll 8
        for (int h = 0; h < 64; h++) a += cl_w2[t * 64 + h] * hr2[h];
        pc[(size_t)n * 17 + t] = a;
    }
}

extern "C" void kernel_launch(void* const* d_in, const int* in_sizes, int n_in,
                              void* d_out, int out_size, void* d_ws, size_t ws_size,
                              hipStream_t stream) {
    const float* x         = (const float*)d_in[0];
    const float* edge_attr = (const float*)d_in[1];
    const int*   edge_idx  = (const int*)d_in[2];
    const float* fmaps     = (const float*)d_in[3];
    const int*   batch_ix  = (const int*)d_in[4];
    const float* ne_w  = (const float*)d_in[5];
    const float* ne_b  = (const float*)d_in[6];
    const float* ee_w  = (const float*)d_in[7];
    const float* ee_b  = (const float*)d_in[8];
    const float* me_w1 = (const float*)d_in[9];
    const float* me_b1 = (const float*)d_in[10];
    const float* me_w2 = (const float*)d_in[11];
    const float* me_b2 = (const float*)d_in[12];
    const float* mn_w  = (const float*)d_in[13];
    const float* mn_b  = (const float*)d_in[14];
    const float* key_w = (const float*)d_in[15];
    const float* key_b = (const float*)d_in[16];
    const float* q_w   = (const float*)d_in[17];
    const float* q_b   = (const float*)d_in[18];
    const float* v_w   = (const float*)d_in[19];
    const float* v_b   = (const float*)d_in[20];
    const float* ec_w1 = (const float*)d_in[21];
    const float* ec_b1 = (const float*)d_in[22];
    const float* ec_w2 = (const float*)d_in[23];
    const float* ec_b2 = (const float*)d_in[24];
    const float* nc_w1 = (const float*)d_in[25];
    const float* nc_b1 = (const float*)d_in[26];
    const float* nc_w2 = (const float*)d_in[27];
    const float* nc_b2 = (const float*)d_in[28];
    const float* cl_w1 = (const float*)d_in[29];
    const float* cl_b1 = (const float*)d_in[30];
    const float* cl_w2 = (const float*)d_in[31];
    const float* cl_b2 = (const float*)d_in[32];

    char* wsp = (char*)d_ws;
    size_t off = 0;
    auto alloc = [&](size_t bytes) -> void* {
        void* p = wsp + off;
        off += (bytes + 255) & ~(size_t)255;
        return p;
    };
    float* q_buf = (float*)alloc((size_t)BATCH * 16 * PPIX * sizeof(float));
    float* v_buf = (float*)alloc((size_t)BATCH * 16 * PPIX * sizeof(float));
    float* nfA   = (float*)alloc((size_t)N_NODES * 128 * sizeof(float));
    float* nfB   = (float*)alloc((size_t)N_NODES * 128 * sizeof(float));
    unsigned short* nf_bf  = (unsigned short*)alloc((size_t)N_NODES * 144 * 2);
    unsigned short* ef_buf = (unsigned short*)alloc((size_t)N_EDGES * 128 * 2);
    unsigned short* w1b = (unsigned short*)alloc(256 * 416 * 2);
    unsigned short* w2b = (unsigned short*)alloc(128 * 256 * 2);
    unsigned short* w3b = (unsigned short*)alloc(128 * 288 * 2);
    unsigned short* w4b = (unsigned short*)alloc(64 * 128 * 2);
    int* hist   = (int*)alloc((2048 + 4) * sizeof(int));   // hist + bcnt (memset together)
    int* bcnt   = hist + 2048;
    int* cursor = (int*)alloc(2048 * sizeof(int));
    int* boff   = (int*)alloc(4 * sizeof(int));
    int* bcur   = (int*)alloc(4 * sizeof(int));
    int* perm   = (int*)alloc((size_t)N_EDGES * sizeof(int));
    int* nperm  = (int*)alloc((size_t)N_NODES * sizeof(int));

    float* pe_out = (float*)d_out;
    float* pn_out = pe_out + N_EDGES;
    float* pc_out = pn_out + N_NODES;
    float* nf_out = pc_out + (size_t)N_NODES * 17;
    float* ef_out = nf_out + (size_t)N_NODES * 128;

    // ---- sort edges by tgt, nodes by batch
    hipMemsetAsync(hist, 0, (2048 + 4) * sizeof(int), stream);
    k_hist<<<N_EDGES / 256, 256, 0, stream>>>(edge_idx, batch_ix, hist, bcnt);
    k_scan<<<1, 256, 0, stream>>>(hist, bcnt, cursor, boff, bcur);
    k_scatter<<<N_EDGES / 256, 256, 0, stream>>>(edge_idx, batch_ix, cursor, bcur, perm, nperm);

    k_wconv<<<416, 256, 0, stream>>>(me_w1, me_w2, mn_w, ec_w1, w1b, w2b, w3b, w4b);
    k_node_enc<<<N_NODES, 128, 0, stream>>>(x, ne_w, ne_b, nfA);
    k_qv<<<64, 256, 0, stream>>>(fmaps, q_w, q_b, v_w, v_b, q_buf, v_buf);
    k_edge_enc<<<N_EDGES / 256, 256, 0, stream>>>(edge_attr, ee_w, ee_b, perm, ef_buf);

    float* cur = nfA;
    float* nxt = nfB;
    for (int step = 0; step < STEPS; step++) {
        k_attn<<<BATCH * 512, 256, 0, stream>>>(cur, q_buf, v_buf, key_w, key_b,
                                                nperm, boff, bcnt, nf_bf, nxt);
        k_mlp<<<N_EDGES / 64, 512, 0, stream>>>(nf_bf, ef_buf, w1b, w2b, w3b,
                                                me_b1, me_b2, mn_b, edge_idx, perm, nxt);
        float* tmp = cur; cur = nxt; nxt = tmp;
    }

    k_edge_head<<<N_EDGES / 32, 256, 0, stream>>>(ef_buf, w4b, ec_b1, ec_w2, ec_b2, perm, pe_out, ef_out);
    k_node_heads<<<N_NODES, 64, 0, stream>>>(cur, nc_w1, nc_b1, nc_w2, nc_b2,
                                             cl_w1, cl_b1, cl_w2, cl_b2, pn_out, pc_out, nf_out);
}

// Round 6
// 732.602 us; speedup vs baseline: 1.1875x; 1.0789x over previous
//
#include <hip/hip_runtime.h>

// Problem constants
#define N_NODES 2048
#define N_EDGES 65536
#define BATCH   4
#define PPIX    4096   // H*W
#define STEPS   4

typedef __attribute__((ext_vector_type(4))) float f32x4;
typedef __attribute__((ext_vector_type(8))) short s16x8;

__device__ __forceinline__ unsigned short f2bf(float f) {
    unsigned u = __float_as_uint(f);
    unsigned r = u + 0x7fffu + ((u >> 16) & 1u);
    return (unsigned short)(r >> 16);
}
__device__ __forceinline__ float bf2f(unsigned short h) {
    return __uint_as_float(((unsigned)h) << 16);
}

// ---------------- sort machinery: counting-sort edges by tgt, nodes by batch ----
__global__ __launch_bounds__(256) void k_hist(const int* __restrict__ ei,
                                              const int* __restrict__ batch_ix,
                                              int* __restrict__ hist,   // 2048 bins (tgt)
                                              int* __restrict__ bcnt) { // 4 bins (batch)
    int i = blockIdx.x * 256 + threadIdx.x;
    if (i < N_EDGES) atomicAdd(&hist[ei[N_EDGES + i]], 1);
    if (i < N_NODES) atomicAdd(&bcnt[batch_ix[i]], 1);
}

__global__ __launch_bounds__(256) void k_scan(const int* __restrict__ hist,
                                              const int* __restrict__ bcnt,
                                              int* __restrict__ cursor,  // 2048: exclusive offsets (consumed by scatter)
                                              int* __restrict__ boff,    // 4: node batch offsets (persist)
                                              int* __restrict__ bcur) {  // 4: scatter cursor for nodes
    __shared__ int tls[256];
    const int t = threadIdx.x;
    int loc[8];
    int s = 0;
#pragma unroll
    for (int j = 0; j < 8; j++) { loc[j] = s; s += hist[t * 8 + j]; }
    tls[t] = s;
    __syncthreads();
    for (int off = 1; off < 256; off <<= 1) {
        int v = (t >= off) ? tls[t - off] : 0;
        __syncthreads();
        tls[t] += v;
        __syncthreads();
    }
    int base = (t > 0) ? tls[t - 1] : 0;
#pragma unroll
    for (int j = 0; j < 8; j++) cursor[t * 8 + j] = base + loc[j];
    if (t == 0) {
        int b = 0;
        for (int i = 0; i < 4; i++) { boff[i] = b; bcur[i] = b; b += bcnt[i]; }
    }
}

__global__ __launch_bounds__(256) void k_scatter(const int* __restrict__ ei,
                                                 const int* __restrict__ batch_ix,
                                                 int* __restrict__ cursor, int* __restrict__ bcur,
                                                 int* __restrict__ perm, int* __restrict__ nperm) {
    int i = blockIdx.x * 256 + threadIdx.x;
    if (i < N_EDGES) {
        int pos = atomicAdd(&cursor[ei[N_EDGES + i]], 1);
        perm[pos] = i;
    }
    if (i < N_NODES) {
        int pos = atomicAdd(&bcur[batch_ix[i]], 1);
        nperm[pos] = i;
    }
}

// ---------------- weight conversion (fp32 -> bf16)
// o1=me_w1 256x416, o2=me_w2 128x256, o3=mn_w 128x272->288pad, o4=ec_w1 64x128,
// o5=ee_w 128x64, o6=ne_w 128x256
__global__ void k_wconv(const float* __restrict__ w1, const float* __restrict__ w2,
                        const float* __restrict__ w3, const float* __restrict__ ec1,
                        const float* __restrict__ eew, const float* __restrict__ new_,
                        unsigned short* __restrict__ o1, unsigned short* __restrict__ o2,
                        unsigned short* __restrict__ o3, unsigned short* __restrict__ o4,
                        unsigned short* __restrict__ o5, unsigned short* __restrict__ o6) {
    int i = blockIdx.x * 256 + threadIdx.x;
    if (i < 256 * 416) o1[i] = f2bf(w1[i]);
    if (i < 128 * 256) o2[i] = f2bf(w2[i]);
    if (i < 128 * 288) {
        int r = i / 288, c = i - r * 288;
        o3[i] = (c < 272) ? f2bf(w3[r * 272 + c]) : (unsigned short)0;
    }
    if (i < 64 * 128) o4[i] = f2bf(ec1[i]);
    if (i < 128 * 64) o5[i] = f2bf(eew[i]);
    if (i < 128 * 256) o6[i] = f2bf(new_[i]);
}

// ---------------- node encoder (MFMA): relu(x @ ne_w.T + ne_b) -> (2048,128) fp32
// 64 nodes/block, 256 threads (4 waves = n-slices of 32 cols), K=256 (8 kc).
__global__ __launch_bounds__(256) void k_node_enc(const float* __restrict__ x,
                                                  const unsigned short* __restrict__ wb,
                                                  const float* __restrict__ b,
                                                  float* __restrict__ out) {
    __shared__ __attribute__((aligned(16))) unsigned short xs2[64 * 264];
    const int tid = threadIdx.x;
    const int n0 = blockIdx.x * 64;
    {
        int row = tid >> 2, qq = tid & 3;
        const float* rp = x + (size_t)(n0 + row) * 256 + qq * 64;
        unsigned short* dp = &xs2[row * 264 + qq * 64];
#pragma unroll
        for (int j = 0; j < 4; j++) {
            float4 f0 = *(const float4*)(rp + j * 16 + 0);
            float4 f1 = *(const float4*)(rp + j * 16 + 4);
            float4 f2 = *(const float4*)(rp + j * 16 + 8);
            float4 f3 = *(const float4*)(rp + j * 16 + 12);
            s16x8 lo, hi;
            lo[0] = (short)f2bf(f0.x); lo[1] = (short)f2bf(f0.y); lo[2] = (short)f2bf(f0.z); lo[3] = (short)f2bf(f0.w);
            lo[4] = (short)f2bf(f1.x); lo[5] = (short)f2bf(f1.y); lo[6] = (short)f2bf(f1.z); lo[7] = (short)f2bf(f1.w);
            hi[0] = (short)f2bf(f2.x); hi[1] = (short)f2bf(f2.y); hi[2] = (short)f2bf(f2.z); hi[3] = (short)f2bf(f2.w);
            hi[4] = (short)f2bf(f3.x); hi[5] = (short)f2bf(f3.y); hi[6] = (short)f2bf(f3.z); hi[7] = (short)f2bf(f3.w);
            *(s16x8*)(dp + j * 16) = lo;
            *(s16x8*)(dp + j * 16 + 8) = hi;
        }
    }
    __syncthreads();
    const int lane = tid & 63;
    const int wn = tid >> 6;
    const int lr = lane & 15;
    const int lk = lane >> 4;
    const f32x4 z4 = {0.f, 0.f, 0.f, 0.f};
    f32x4 acc[4][2];
#pragma unroll
    for (int mt = 0; mt < 4; mt++)
#pragma unroll
        for (int nt = 0; nt < 2; nt++) acc[mt][nt] = z4;
#pragma unroll
    for (int kc = 0; kc < 8; kc++) {
        s16x8 a0 = *(const s16x8*)&xs2[(0 + lr) * 264 + kc * 32 + lk * 8];
        s16x8 a1 = *(const s16x8*)&xs2[(16 + lr) * 264 + kc * 32 + lk * 8];
        s16x8 a2 = *(const s16x8*)&xs2[(32 + lr) * 264 + kc * 32 + lk * 8];
        s16x8 a3 = *(const s16x8*)&xs2[(48 + lr) * 264 + kc * 32 + lk * 8];
#pragma unroll
        for (int nt = 0; nt < 2; nt++) {
            int nn = wn * 32 + nt * 16 + lr;
            s16x8 bf = *(const s16x8*)&wb[(size_t)nn * 256 + kc * 32 + lk * 8];
            acc[0][nt] = __builtin_amdgcn_mfma_f32_16x16x32_bf16(a0, bf, acc[0][nt], 0, 0, 0);
            acc[1][nt] = __builtin_amdgcn_mfma_f32_16x16x32_bf16(a1, bf, acc[1][nt], 0, 0, 0);
            acc[2][nt] = __builtin_amdgcn_mfma_f32_16x16x32_bf16(a2, bf, acc[2][nt], 0, 0, 0);
            acc[3][nt] = __builtin_amdgcn_mfma_f32_16x16x32_bf16(a3, bf, acc[3][nt], 0, 0, 0);
        }
    }
#pragma unroll
    for (int nt = 0; nt < 2; nt++) {
        int nn = wn * 32 + nt * 16 + lr;
        float bias = b[nn];
#pragma unroll
        for (int mt = 0; mt < 4; mt++)
#pragma unroll
            for (int r = 0; r < 4; r++) {
                int m = mt * 16 + lk * 4 + r;
                out[(size_t)(n0 + m) * 128 + nn] = fmaxf(acc[mt][nt][r] + bias, 0.f);
            }
    }
}

// ---------------- edge encoder (MFMA, writes ef in SORTED slot order)
// 64 edges/block, 256 threads (4 waves = n-slices of 32 cols), K=64 (2 kc).
__global__ __launch_bounds__(256) void k_edge_enc(const float* __restrict__ ea,
                                                  const unsigned short* __restrict__ wb,
                                                  const float* __restrict__ b,
                                                  const int* __restrict__ perm,
                                                  unsigned short* __restrict__ ef) {
    __shared__ __attribute__((aligned(16))) unsigned short eas[64 * 72];
    __shared__ int ep[64];
    const int tid = threadIdx.x;
    const int e0 = blockIdx.x * 64;
    if (tid < 64) ep[tid] = perm[e0 + tid];
    __syncthreads();
    {
        int row = tid >> 2, qq = tid & 3;
        const float* rp = ea + (size_t)ep[row] * 64 + qq * 16;
        float4 f0 = *(const float4*)(rp + 0);
        float4 f1 = *(const float4*)(rp + 4);
        float4 f2 = *(const float4*)(rp + 8);
        float4 f3 = *(const float4*)(rp + 12);
        s16x8 lo, hi;
        lo[0] = (short)f2bf(f0.x); lo[1] = (short)f2bf(f0.y); lo[2] = (short)f2bf(f0.z); lo[3] = (short)f2bf(f0.w);
        lo[4] = (short)f2bf(f1.x); lo[5] = (short)f2bf(f1.y); lo[6] = (short)f2bf(f1.z); lo[7] = (short)f2bf(f1.w);
        hi[0] = (short)f2bf(f2.x); hi[1] = (short)f2bf(f2.y); hi[2] = (short)f2bf(f2.z); hi[3] = (short)f2bf(f2.w);
        hi[4] = (short)f2bf(f3.x); hi[5] = (short)f2bf(f3.y); hi[6] = (short)f2bf(f3.z); hi[7] = (short)f2bf(f3.w);
        unsigned short* dp = &eas[row * 72 + qq * 16];
        *(s16x8*)(dp) = lo;
        *(s16x8*)(dp + 8) = hi;
    }
    __syncthreads();
    const int lane = tid & 63;
    const int wn = tid >> 6;
    const int lr = lane & 15;
    const int lk = lane >> 4;
    const f32x4 z4 = {0.f, 0.f, 0.f, 0.f};
    f32x4 acc[4][2];
#pragma unroll
    for (int mt = 0; mt < 4; mt++)
#pragma unroll
        for (int nt = 0; nt < 2; nt++) acc[mt][nt] = z4;
#pragma unroll
    for (int kc = 0; kc < 2; kc++) {
        s16x8 a0 = *(const s16x8*)&eas[(0 + lr) * 72 + kc * 32 + lk * 8];
        s16x8 a1 = *(const s16x8*)&eas[(16 + lr) * 72 + kc * 32 + lk * 8];
        s16x8 a2 = *(const s16x8*)&eas[(32 + lr) * 72 + kc * 32 + lk * 8];
        s16x8 a3 = *(const s16x8*)&eas[(48 + lr) * 72 + kc * 32 + lk * 8];
#pragma unroll
        for (int nt = 0; nt < 2; nt++) {
            int nn = wn * 32 + nt * 16 + lr;
            s16x8 bf = *(const s16x8*)&wb[(size_t)nn * 64 + kc * 32 + lk * 8];
            acc[0][nt] = __builtin_amdgcn_mfma_f32_16x16x32_bf16(a0, bf, acc[0][nt], 0, 0, 0);
            acc[1][nt] = __builtin_amdgcn_mfma_f32_16x16x32_bf16(a1, bf, acc[1][nt], 0, 0, 0);
            acc[2][nt] = __builtin_amdgcn_mfma_f32_16x16x32_bf16(a2, bf, acc[2][nt], 0, 0, 0);
            acc[3][nt] = __builtin_amdgcn_mfma_f32_16x16x32_bf16(a3, bf, acc[3][nt], 0, 0, 0);
        }
    }
#pragma unroll
    for (int nt = 0; nt < 2; nt++) {
        int nn = wn * 32 + nt * 16 + lr;
        float bias = b[nn];
#pragma unroll
        for (int mt = 0; mt < 4; mt++)
#pragma unroll
            for (int r = 0; r < 4; r++) {
                int m = mt * 16 + lk * 4 + r;
                ef[(size_t)(e0 + m) * 128 + nn] = f2bf(fmaxf(acc[mt][nt][r] + bias, 0.f));
            }
    }
}

// ---------------- queries/values: einsum('oc,bcp->bop') + bias
__global__ __launch_bounds__(256) void k_qv(const float* __restrict__ fm,
                                            const float* __restrict__ qw, const float* __restrict__ qb,
                                            const float* __restrict__ vw, const float* __restrict__ vb,
                                            float* __restrict__ q, float* __restrict__ v) {
    __shared__ float fs[32][256];
    const int b = blockIdx.x >> 4;
    const int pt = blockIdx.x & 15;
    for (int i = threadIdx.x; i < 32 * 256; i += 256) {
        int c = i >> 8, p = i & 255;
        fs[c][p] = fm[(size_t)b * 32 * PPIX + (size_t)c * PPIX + pt * 256 + p];
    }
    __syncthreads();
    const int p = threadIdx.x;
    for (int o = 0; o < 16; o++) {
        float qa = qb[o], va = vb[o];
#pragma unroll
        for (int c = 0; c < 32; c++) {
            float f = fs[c][p];
            qa += qw[o * 32 + c] * f;
            va += vw[o * 32 + c] * f;
        }
        size_t oidx = ((size_t)b * 16 + o) * PPIX + pt * 256 + p;
        q[oidx] = qa;
        v[oidx] = va;
    }
}

// ---------------- attention: 4 nodes/block (same batch), TWO-PASS softmax.
// Pass A: scores in registers (fully unrolled -> static indices), hierarchical max.
// Pass B: exp + weighted V accumulate, hierarchical sum. No divergent rescale.
// Also zeroes the next-step node accumulator rows (replaces a memset dispatch).
__global__ __launch_bounds__(256) void k_attn(const float* __restrict__ nf,
                                              const float* __restrict__ qbuf,
                                              const float* __restrict__ vbuf,
                                              const float* __restrict__ key_w,
                                              const float* __restrict__ key_b,
                                              const int* __restrict__ nperm,
                                              const int* __restrict__ boff,
                                              const int* __restrict__ bcnt,
                                              unsigned short* __restrict__ nf_bf,
                                              float* __restrict__ nxt) {
    const int b = blockIdx.x >> 9;       // grid = 4 * 512
    const int chunk = blockIdx.x & 511;
    const int cnt = bcnt[b];
    if (chunk * 4 >= cnt) return;
    const int base = boff[b] + chunk * 4;
    const int nvalid = min(4, cnt - chunk * 4);
    const int t = threadIdx.x;

    __shared__ int nid[4];
    __shared__ float xs[4][128];
    __shared__ float ks[4][16];
    __shared__ float redm[4][4];       // [wave][node] partial max
    __shared__ float pbuf[4][4][17];   // [wave][node][wsum, vacc16]

    if (t < 4) nid[t] = nperm[base + ((t < nvalid) ? t : 0)];
    __syncthreads();
    for (int i2 = t; i2 < 4 * 128; i2 += 256) {
        int i = i2 >> 7, d = i2 & 127;
        xs[i][d] = nf[(size_t)nid[i] * 128 + d];
        if (i < nvalid) nxt[(size_t)nid[i] * 128 + d] = 0.f;   // zero next accumulator
    }
    __syncthreads();
    if (t < 64) {
        int i = t >> 4, a = t & 15;
        const float* wr = key_w + a * 128;
        float acc = key_b[a];
#pragma unroll 8
        for (int c = 0; c < 128; c++) acc += xs[i][c] * wr[c];
        ks[i][a] = acc;
    }
    __syncthreads();
    float kk[4][16];
#pragma unroll
    for (int i = 0; i < 4; i++)
#pragma unroll
        for (int a = 0; a < 16; a++) kk[i][a] = ks[i][a];

    const float* q = qbuf + (size_t)b * 16 * PPIX;
    const float* v = vbuf + (size_t)b * 16 * PPIX;

    // ---- pass A: scores + max
    float s[4][16];
    float m[4] = {-3e38f, -3e38f, -3e38f, -3e38f};
#pragma unroll
    for (int ch = 0; ch < 16; ch++) {
        int p = ch * 256 + t;
        float qv[16];
#pragma unroll
        for (int a = 0; a < 16; a++) qv[a] = q[a * PPIX + p];
#pragma unroll
        for (int i = 0; i < 4; i++) {
            float acc = 0.f;
#pragma unroll
            for (int a = 0; a < 16; a++) acc += kk[i][a] * qv[a];
            s[i][ch] = acc;
            m[i] = fmaxf(m[i], acc);
        }
    }
#pragma unroll
    for (int off = 1; off < 64; off <<= 1)
#pragma unroll
        for (int i = 0; i < 4; i++) m[i] = fmaxf(m[i], __shfl_xor(m[i], off));
    const int wv = t >> 6;
    if ((t & 63) == 0) {
#pragma unroll
        for (int i = 0; i < 4; i++) redm[wv][i] = m[i];
    }
    __syncthreads();
    float mf[4];
#pragma unroll
    for (int i = 0; i < 4; i++)
        mf[i] = fmaxf(fmaxf(redm[0][i], redm[1][i]), fmaxf(redm[2][i], redm[3][i]));

    // ---- pass B: exp + weighted V
    float wsm[4] = {0.f, 0.f, 0.f, 0.f};
    float vacc[4][16];
#pragma unroll
    for (int i = 0; i < 4; i++)
#pragma unroll
        for (int a = 0; a < 16; a++) vacc[i][a] = 0.f;
#pragma unroll
    for (int ch = 0; ch < 16; ch++) {
        int p = ch * 256 + t;
        float vv[16];
#pragma unroll
        for (int a = 0; a < 16; a++) vv[a] = v[a * PPIX + p];
#pragma unroll
        for (int i = 0; i < 4; i++) {
            float w = __expf(s[i][ch] - mf[i]);
            wsm[i] += w;
#pragma unroll
            for (int a = 0; a < 16; a++) vacc[i][a] += w * vv[a];
        }
    }
#pragma unroll
    for (int off = 1; off < 64; off <<= 1)
#pragma unroll
        for (int i = 0; i < 4; i++) {
            wsm[i] += __shfl_xor(wsm[i], off);
#pragma unroll
            for (int a = 0; a < 16; a++) vacc[i][a] += __shfl_xor(vacc[i][a], off);
        }
    if ((t & 63) == 0) {
#pragma unroll
        for (int i = 0; i < 4; i++) {
            pbuf[wv][i][0] = wsm[i];
#pragma unroll
            for (int a = 0; a < 16; a++) pbuf[wv][i][1 + a] = vacc[i][a];
        }
    }
    __syncthreads();
    if (t < 64) {
        int i = t >> 4, a = t & 15;
        float den = pbuf[0][i][0] + pbuf[1][i][0] + pbuf[2][i][0] + pbuf[3][i][0];
        float num = pbuf[0][i][1 + a] + pbuf[1][i][1 + a] + pbuf[2][i][1 + a] + pbuf[3][i][1 + a];
        if (i < nvalid) nf_bf[(size_t)nid[i] * 144 + 128 + a] = f2bf(num / den);
    }
    // pack x part
    for (int i2 = t; i2 < 4 * 128; i2 += 256) {
        int i = i2 >> 7, d = i2 & 127;
        if (i < nvalid) nf_bf[(size_t)nid[i] * 144 + d] = f2bf(xs[i][d]);
    }
}

// ---------------- fused 3-layer edge MLP + segment-reduced message scatter
// tile = 64 SORTED edges, 512 threads (8 waves): wave = (m-half wm) x (n-slice wn).
__global__ __launch_bounds__(512, 4) void k_mlp(const unsigned short* __restrict__ nf_bf,
                                                unsigned short* __restrict__ ef_buf,
                                                const unsigned short* __restrict__ w1b,
                                                const unsigned short* __restrict__ w2b,
                                                const unsigned short* __restrict__ w3b,
                                                const float* __restrict__ me_b1,
                                                const float* __restrict__ me_b2,
                                                const float* __restrict__ mn_b,
                                                const int* __restrict__ ei,
                                                const int* __restrict__ perm,
                                                float* __restrict__ node_acc) {
    __shared__ __attribute__((aligned(16))) unsigned short catA[64 * 424]; // [x_i 0:144 | x_j 144:288 | ef 288:416 | pad]
    __shared__ int tgt_s[64];
    __shared__ int src_s[64];
    const int tid = threadIdx.x;
    const int e0 = blockIdx.x * 64;
    const int* srcI = ei;
    const int* tgtI = ei + N_EDGES;
    if (tid < 64) {
        int eg = perm[e0 + tid];
        tgt_s[tid] = tgtI[eg];
        src_s[tid] = srcI[eg];
    }
    __syncthreads();
    // gather staging: 52 x 16B chunks per edge, 64 edges
    for (int c = tid; c < 64 * 52; c += 512) {
        int e = c / 52;
        int r = c - e * 52;
        const unsigned short* sp;
        int dcol;
        if (r < 18)      { sp = nf_bf + (size_t)tgt_s[e] * 144 + r * 8;        dcol = r * 8; }
        else if (r < 36) { sp = nf_bf + (size_t)src_s[e] * 144 + (r - 18) * 8; dcol = 144 + (r - 18) * 8; }
        else             { sp = ef_buf + (size_t)(e0 + e) * 128 + (r - 36) * 8; dcol = 288 + (r - 36) * 8; }
        *(s16x8*)&catA[e * 424 + dcol] = *(const s16x8*)sp;
    }
    __syncthreads();

    const int lane = tid & 63;
    const int wid = tid >> 6;       // 0..7
    const int wm = wid >> 2;        // m-half: rows [wm*32, wm*32+32)
    const int wn = wid & 3;         // n-slice
    const int lr = lane & 15;
    const int lk = lane >> 4;
    const int rbase = wm * 32;
    const f32x4 z4 = {0.f, 0.f, 0.f, 0.f};

    // ---- layer 1: (64 x 416) @ (416 x 256); wave: rows rbase..+32, cols wn*64..+64
    f32x4 acc[2][4];
    for (int mt = 0; mt < 2; mt++)
        for (int nt = 0; nt < 4; nt++) acc[mt][nt] = z4;
#pragma unroll 2
    for (int kc = 0; kc < 13; kc++) {
        s16x8 a0 = *(const s16x8*)&catA[(rbase + lr) * 424 + kc * 32 + lk * 8];
        s16x8 a1 = *(const s16x8*)&catA[(rbase + 16 + lr) * 424 + kc * 32 + lk * 8];
#pragma unroll
        for (int nt = 0; nt < 4; nt++) {
            int nn = wn * 64 + nt * 16 + lr;
            s16x8 b = *(const s16x8*)&w1b[(size_t)nn * 416 + kc * 32 + lk * 8];
            acc[0][nt] = __builtin_amdgcn_mfma_f32_16x16x32_bf16(a0, b, acc[0][nt], 0, 0, 0);
            acc[1][nt] = __builtin_amdgcn_mfma_f32_16x16x32_bf16(a1, b, acc[1][nt], 0, 0, 0);
        }
    }
    __syncthreads();   // all L1 reads of catA done -> cols 144:416 now dead
#pragma unroll
    for (int nt = 0; nt < 4; nt++) {
        int nn = wn * 64 + nt * 16 + lr;
        float bias = me_b1[nn];
#pragma unroll
        for (int mt = 0; mt < 2; mt++)
#pragma unroll
            for (int r = 0; r < 4; r++) {
                int m = rbase + mt * 16 + lk * 4 + r;
                catA[m * 424 + 144 + nn] = f2bf(fmaxf(acc[mt][nt][r] + bias, 0.f));
            }
    }
    __syncthreads();

    // ---- layer 2: (64 x 256) @ (256 x 128) -> acc2 (regs); cols wn*32..+32
    f32x4 acc2[2][2];
    for (int mt = 0; mt < 2; mt++)
        for (int nt = 0; nt < 2; nt++) acc2[mt][nt] = z4;
#pragma unroll 2
    for (int kc = 0; kc < 8; kc++) {
        s16x8 a0 = *(const s16x8*)&catA[(rbase + lr) * 424 + 144 + kc * 32 + lk * 8];
        s16x8 a1 = *(const s16x8*)&catA[(rbase + 16 + lr) * 424 + 144 + kc * 32 + lk * 8];
#pragma unroll
        for (int nt = 0; nt < 2; nt++) {
            int nn = wn * 32 + nt * 16 + lr;
            s16x8 b = *(const s16x8*)&w2b[(size_t)nn * 256 + kc * 32 + lk * 8];
            acc2[0][nt] = __builtin_amdgcn_mfma_f32_16x16x32_bf16(a0, b, acc2[0][nt], 0, 0, 0);
            acc2[1][nt] = __builtin_amdgcn_mfma_f32_16x16x32_bf16(a1, b, acc2[1][nt], 0, 0, 0);
        }
    }
    __syncthreads();   // all L2 reads of out1 overlay done
#pragma unroll
    for (int nt = 0; nt < 2; nt++) {
        int nn = wn * 32 + nt * 16 + lr;
        float bias = me_b2[nn];
#pragma unroll
        for (int mt = 0; mt < 2; mt++)
#pragma unroll
            for (int r = 0; r < 4; r++) {
                int m = rbase + mt * 16 + lk * 4 + r;
                catA[m * 424 + 144 + nn] = f2bf(fmaxf(acc2[mt][nt][r] + bias, 0.f));
            }
    }
    __syncthreads();

    // ---- layer 3: (64 x 288) @ (288 x 128) -> acc3 (regs). cols 272:288 junk x zero-weights.
    f32x4 acc3[2][2];
    for (int mt = 0; mt < 2; mt++)
        for (int nt = 0; nt < 2; nt++) acc3[mt][nt] = z4;
#pragma unroll 2
    for (int kc = 0; kc < 9; kc++) {
        s16x8 a0 = *(const s16x8*)&catA[(rbase + lr) * 424 + kc * 32 + lk * 8];
        s16x8 a1 = *(const s16x8*)&catA[(rbase + 16 + lr) * 424 + kc * 32 + lk * 8];
#pragma unroll
        for (int nt = 0; nt < 2; nt++) {
            int nn = wn * 32 + nt * 16 + lr;
            s16x8 b = *(const s16x8*)&w3b[(size_t)nn * 288 + kc * 32 + lk * 8];
            acc3[0][nt] = __builtin_amdgcn_mfma_f32_16x16x32_bf16(a0, b, acc3[0][nt], 0, 0, 0);
            acc3[1][nt] = __builtin_amdgcn_mfma_f32_16x16x32_bf16(a1, b, acc3[1][nt], 0, 0, 0);
        }
    }
    __syncthreads();   // all L3 reads of catA done -> overlay free for msg (fp32)
#pragma unroll
    for (int nt = 0; nt < 2; nt++) {
        int nn = wn * 32 + nt * 16 + lr;
        float bias = mn_b[nn];
#pragma unroll
        for (int mt = 0; mt < 2; mt++)
#pragma unroll
            for (int r = 0; r < 4; r++) {
                int m = rbase + mt * 16 + lk * 4 + r;
                *(float*)&catA[m * 424 + 144 + nn * 2] = fmaxf(acc3[mt][nt][r] + bias, 0.f);
            }
    }
    __syncthreads();
    // segment-reduce: sorted tgt -> runs; 512 threads = 128 cols x 4 row-chunks of 16
    {
        const int c = tid & 127;
        const int r0 = (tid >> 7) * 16;
        float run = *(const float*)&catA[r0 * 424 + 144 + c * 2];
        int prev = tgt_s[r0];
        for (int r = r0 + 1; r < r0 + 16; r++) {
            int tg = tgt_s[r];
            float val = *(const float*)&catA[r * 424 + 144 + c * 2];
            if (tg != prev) {
                atomicAdd(&node_acc[(size_t)prev * 128 + c], run);
                run = val;
                prev = tg;
            } else {
                run += val;
            }
        }
        atomicAdd(&node_acc[(size_t)prev * 128 + c], run);
    }
    // deferred global ef write (from acc2 regs; no barrier after -> no drain stall)
#pragma unroll
    for (int nt = 0; nt < 2; nt++) {
        int nn = wn * 32 + nt * 16 + lr;
        float bias = me_b2[nn];
#pragma unroll
        for (int mt = 0; mt < 2; mt++)
#pragma unroll
            for (int r = 0; r < 4; r++) {
                int m = rbase + mt * 16 + lk * 4 + r;
                ef_buf[(size_t)(e0 + m) * 128 + nn] = f2bf(fmaxf(acc2[mt][nt][r] + bias, 0.f));
            }
    }
}

// ---------------- edge head (MFMA): pe + fp32 edge_features output (unsorts via perm)
__global__ __launch_bounds__(256) void k_edge_head(const unsigned short* __restrict__ ef,
                                                   const unsigned short* __restrict__ w1b,
                                                   const float* __restrict__ b1,
                                                   const float* __restrict__ w2,
                                                   const float* __restrict__ b2,
                                                   const int* __restrict__ perm,
                                                   float* __restrict__ pe,
                                                   float* __restrict__ ef_out) {
    __shared__ __attribute__((aligned(16))) unsigned short efs[32][136];
    __shared__ float h_s[32][68];
    __shared__ int ep_s[32];
    const int tid = threadIdx.x;
    const int e0 = blockIdx.x * 32;
    if (tid < 32) ep_s[tid] = perm[e0 + tid];
    __syncthreads();
    // stage 32x128 bf16 tile + write fp32 ef_out (at original edge index)
    for (int c = tid; c < 32 * 16; c += 256) {
        int e = c >> 4, r = c & 15;
        s16x8 v = *(const s16x8*)&ef[(size_t)(e0 + e) * 128 + r * 8];
        *(s16x8*)&efs[e][r * 8] = v;
        float4 lo, hi;
        lo.x = bf2f((unsigned short)v[0]); lo.y = bf2f((unsigned short)v[1]);
        lo.z = bf2f((unsigned short)v[2]); lo.w = bf2f((unsigned short)v[3]);
        hi.x = bf2f((unsigned short)v[4]); hi.y = bf2f((unsigned short)v[5]);
        hi.z = bf2f((unsigned short)v[6]); hi.w = bf2f((unsigned short)v[7]);
        size_t ob = (size_t)ep_s[e] * 128 + r * 8;
        *(float4*)&ef_out[ob] = lo;
        *(float4*)&ef_out[ob + 4] = hi;
    }
    __syncthreads();
    const int lane = tid & 63;
    const int wid = tid >> 6;   // owns h block wid*16
    const int lr = lane & 15;
    const int lk = lane >> 4;
    const f32x4 z4 = {0.f, 0.f, 0.f, 0.f};
    f32x4 acc0 = z4, acc1 = z4;
    for (int kc = 0; kc < 4; kc++) {
        s16x8 a0 = *(const s16x8*)&efs[lr][kc * 32 + lk * 8];
        s16x8 a1 = *(const s16x8*)&efs[16 + lr][kc * 32 + lk * 8];
        s16x8 b = *(const s16x8*)&w1b[(size_t)(wid * 16 + lr) * 128 + kc * 32 + lk * 8];
        acc0 = __builtin_amdgcn_mfma_f32_16x16x32_bf16(a0, b, acc0, 0, 0, 0);
        acc1 = __builtin_amdgcn_mfma_f32_16x16x32_bf16(a1, b, acc1, 0, 0, 0);
    }
    {
        int h = wid * 16 + lr;
        float bias = b1[h];
#pragma unroll
        for (int r = 0; r < 4; r++) {
            h_s[lk * 4 + r][h]      = fmaxf(acc0[r] + bias, 0.f);
            h_s[16 + lk * 4 + r][h] = fmaxf(acc1[r] + bias, 0.f);
        }
    }
    __syncthreads();
    if (tid < 32) {
        float a = b2[0];
#pragma unroll 8
        for (int h = 0; h < 64; h++) a += w2[h] * h_s[tid][h];
        pe[ep_s[tid]] = a;
    }
}

// ---------------- fused node heads: pn, pc, nf_out. One wave per node.
__global__ __launch_bounds__(64) void k_node_heads(const float* __restrict__ nf,
                                                   const float* __restrict__ nc_w1, const float* __restrict__ nc_b1,
                                                   const float* __restrict__ nc_w2, const float* __restrict__ nc_b2,
                                                   const float* __restrict__ cl_w1, const float* __restrict__ cl_b1,
                                                   const float* __restrict__ cl_w2, const float* __restrict__ cl_b2,
                                                   float* __restrict__ pn, float* __restrict__ pc,
                                                   float* __restrict__ nf_out) {
    __shared__ float xs[128];
    __shared__ float hr2[64];
    const int n = blockIdx.x;
    const int t = threadIdx.x;
    float2 xv = *(const float2*)&nf[(size_t)n * 128 + t * 2];
    xs[t * 2] = xv.x;
    xs[t * 2 + 1] = xv.y;
    *(float2*)&nf_out[(size_t)n * 128 + t * 2] = xv;
    __syncthreads();
    float a1 = nc_b1[t], a2 = cl_b1[t];
#pragma unroll 8
    for (int d4 = 0; d4 < 32; d4++) {
        float4 w1v = *(const float4*)&nc_w1[(size_t)t * 128 + d4 * 4];
        float4 w2v = *(const float4*)&cl_w1[(size_t)t * 128 + d4 * 4];
        float x0 = xs[d4 * 4], x1 = xs[d4 * 4 + 1], x2 = xs[d4 * 4 + 2], x3 = xs[d4 * 4 + 3];
        a1 += x0 * w1v.x + x1 * w1v.y + x2 * w1v.z + x3 * w1v.w;
        a2 += x0 * w2v.x + x1 * w2v.y + x2 * w2v.z + x3 * w2v.w;
    }
    float h1 = fmaxf(a1, 0.f);
    hr2[t] = fmaxf(a2, 0.f);
    float p = nc_w2[t] * h1;
#pragma unroll
    for (int off = 32; off > 0; off >>= 1) p += __shfl_down(p, off);
    if (t == 0) pn[n] = p + nc_b2[0];
    __syncthreads();
    if (t < 17) {
        float a = cl_b2[t];
#pragma unroll 8
        for (int h = 0; h < 64; h++) a += cl_w2[t * 64 + h] * hr2[h];
        pc[(size_t)n * 17 + t] = a;
    }
}

extern "C" void kernel_launch(void* const* d_in, const int* in_sizes, int n_in,
                              void* d_out, int out_size, void* d_ws, size_t ws_size,
                              hipStream_t stream) {
    const float* x         = (const float*)d_in[0];
    const float* edge_attr = (const float*)d_in[1];
    const int*   edge_idx  = (const int*)d_in[2];
    const float* fmaps     = (const float*)d_in[3];
    const int*   batch_ix  = (const int*)d_in[4];
    const float* ne_w  = (const float*)d_in[5];
    const float* ne_b  = (const float*)d_in[6];
    const float* ee_w  = (const float*)d_in[7];
    const float* ee_b  = (const float*)d_in[8];
    const float* me_w1 = (const float*)d_in[9];
    const float* me_b1 = (const float*)d_in[10];
    const float* me_w2 = (const float*)d_in[11];
    const float* me_b2 = (const float*)d_in[12];
    const float* mn_w  = (const float*)d_in[13];
    const float* mn_b  = (const float*)d_in[14];
    const float* key_w = (const float*)d_in[15];
    const float* key_b = (const float*)d_in[16];
    const float* q_w   = (const float*)d_in[17];
    const float* q_b   = (const float*)d_in[18];
    const float* v_w   = (const float*)d_in[19];
    const float* v_b   = (const float*)d_in[20];
    const float* ec_w1 = (const float*)d_in[21];
    const float* ec_b1 = (const float*)d_in[22];
    const float* ec_w2 = (const float*)d_in[23];
    const float* ec_b2 = (const float*)d_in[24];
    const float* nc_w1 = (const float*)d_in[25];
    const float* nc_b1 = (const float*)d_in[26];
    const float* nc_w2 = (const float*)d_in[27];
    const float* nc_b2 = (const float*)d_in[28];
    const float* cl_w1 = (const float*)d_in[29];
    const float* cl_b1 = (const float*)d_in[30];
    const float* cl_w2 = (const float*)d_in[31];
    const float* cl_b2 = (const float*)d_in[32];

    char* wsp = (char*)d_ws;
    size_t off = 0;
    auto alloc = [&](size_t bytes) -> void* {
        void* p = wsp + off;
        off += (bytes + 255) & ~(size_t)255;
        return p;
    };
    float* q_buf = (float*)alloc((size_t)BATCH * 16 * PPIX * sizeof(float));
    float* v_buf = (float*)alloc((size_t)BATCH * 16 * PPIX * sizeof(float));
    float* nfA   = (float*)alloc((size_t)N_NODES * 128 * sizeof(float));
    float* nfB   = (float*)alloc((size_t)N_NODES * 128 * sizeof(float));
    unsigned short* nf_bf  = (unsigned short*)alloc((size_t)N_NODES * 144 * 2);
    unsigned short* ef_buf = (unsigned short*)alloc((size_t)N_EDGES * 128 * 2);
    unsigned short* w1b = (unsigned short*)alloc(256 * 416 * 2);
    unsigned short* w2b = (unsigned short*)alloc(128 * 256 * 2);
    unsigned short* w3b = (unsigned short*)alloc(128 * 288 * 2);
    unsigned short* w4b = (unsigned short*)alloc(64 * 128 * 2);
    unsigned short* w5b = (unsigned short*)alloc(128 * 64 * 2);
    unsigned short* w6b = (unsigned short*)alloc(128 * 256 * 2);
    int* hist   = (int*)alloc((2048 + 4) * sizeof(int));   // hist + bcnt (memset together)
    int* bcnt   = hist + 2048;
    int* cursor = (int*)alloc(2048 * sizeof(int));
    int* boff   = (int*)alloc(4 * sizeof(int));
    int* bcur   = (int*)alloc(4 * sizeof(int));
    int* perm   = (int*)alloc((size_t)N_EDGES * sizeof(int));
    int* nperm  = (int*)alloc((size_t)N_NODES * sizeof(int));

    float* pe_out = (float*)d_out;
    float* pn_out = pe_out + N_EDGES;
    float* pc_out = pn_out + N_NODES;
    float* nf_out = pc_out + (size_t)N_NODES * 17;
    float* ef_out = nf_out + (size_t)N_NODES * 128;

    // ---- sort edges by tgt, nodes by batch
    hipMemsetAsync(hist, 0, (2048 + 4) * sizeof(int), stream);
    k_hist<<<N_EDGES / 256, 256, 0, stream>>>(edge_idx, batch_ix, hist, bcnt);
    k_scan<<<1, 256, 0, stream>>>(hist, bcnt, cursor, boff, bcur);
    k_scatter<<<N_EDGES / 256, 256, 0, stream>>>(edge_idx, batch_ix, cursor, bcur, perm, nperm);

    k_wconv<<<416, 256, 0, stream>>>(me_w1, me_w2, mn_w, ec_w1, ee_w, ne_w,
                                     w1b, w2b, w3b, w4b, w5b, w6b);
    k_node_enc<<<N_NODES / 64, 256, 0, stream>>>(x, w6b, ne_b, nfA);
    k_qv<<<64, 256, 0, stream>>>(fmaps, q_w, q_b, v_w, v_b, q_buf, v_buf);
    k_edge_enc<<<N_EDGES / 64, 256, 0, stream>>>(edge_attr, w5b, ee_b, perm, ef_buf);

    float* cur = nfA;
    float* nxt = nfB;
    for (int step = 0; step < STEPS; step++) {
        k_attn<<<BATCH * 512, 256, 0, stream>>>(cur, q_buf, v_buf, key_w, key_b,
                                                nperm, boff, bcnt, nf_bf, nxt);
        k_mlp<<<N_EDGES / 64, 512, 0, stream>>>(nf_bf, ef_buf, w1b, w2b, w3b,
                                                me_b1, me_b2, mn_b, edge_idx, perm, nxt);
        float* tmp = cur; cur = nxt; nxt = tmp;
    }

    k_edge_head<<<N_EDGES / 32, 256, 0, stream>>>(ef_buf, w4b, ec_b1, ec_w2, ec_b2, perm, pe_out, ef_out);
    k_node_heads<<<N_NODES, 64, 0, stream>>>(cur, nc_w1, nc_b1, nc_w2, nc_b2,
                                             cl_w1, cl_b1, cl_w2, cl_b2, pn_out, pc_out, nf_out);
}

// Round 8
// 669.519 us; speedup vs baseline: 1.2994x; 1.0942x over previous
//
#include <hip/hip_runtime.h>

// Problem constants
#define N_NODES 2048
#define N_EDGES 65536
#define BATCH   4
#define PPIX    4096   // H*W
#define STEPS   4

typedef __attribute__((ext_vector_type(4))) float f32x4;
typedef __attribute__((ext_vector_type(8))) short s16x8;

__device__ __forceinline__ unsigned short f2bf(float f) {
    unsigned u = __float_as_uint(f);
    unsigned r = u + 0x7fffu + ((u >> 16) & 1u);
    return (unsigned short)(r >> 16);
}
__device__ __forceinline__ float bf2f(unsigned short h) {
    return __uint_as_float(((unsigned)h) << 16);
}

// ---------------- sort machinery: counting-sort edges by tgt, nodes by batch ----
__global__ __launch_bounds__(256) void k_hist(const int* __restrict__ ei,
                                              const int* __restrict__ batch_ix,
                                              int* __restrict__ hist,   // 2048 bins (tgt)
                                              int* __restrict__ bcnt) { // 4 bins (batch)
    int i = blockIdx.x * 256 + threadIdx.x;
    if (i < N_EDGES) atomicAdd(&hist[ei[N_EDGES + i]], 1);
    if (i < N_NODES) atomicAdd(&bcnt[batch_ix[i]], 1);
}

__global__ __launch_bounds__(256) void k_scan(const int* __restrict__ hist,
                                              const int* __restrict__ bcnt,
                                              int* __restrict__ cursor,  // 2048: exclusive offsets (consumed by scatter)
                                              int* __restrict__ boff,    // 4: node batch offsets (persist)
                                              int* __restrict__ bcur) {  // 4: scatter cursor for nodes
    __shared__ int tls[256];
    const int t = threadIdx.x;
    int loc[8];
    int s = 0;
#pragma unroll
    for (int j = 0; j < 8; j++) { loc[j] = s; s += hist[t * 8 + j]; }
    tls[t] = s;
    __syncthreads();
    for (int off = 1; off < 256; off <<= 1) {
        int v = (t >= off) ? tls[t - off] : 0;
        __syncthreads();
        tls[t] += v;
        __syncthreads();
    }
    int base = (t > 0) ? tls[t - 1] : 0;
#pragma unroll
    for (int j = 0; j < 8; j++) cursor[t * 8 + j] = base + loc[j];
    if (t == 0) {
        int b = 0;
        for (int i = 0; i < 4; i++) { boff[i] = b; bcur[i] = b; b += bcnt[i]; }
    }
}

__global__ __launch_bounds__(256) void k_scatter(const int* __restrict__ ei,
                                                 const int* __restrict__ batch_ix,
                                                 int* __restrict__ cursor, int* __restrict__ bcur,
                                                 int* __restrict__ perm, int* __restrict__ nperm) {
    int i = blockIdx.x * 256 + threadIdx.x;
    if (i < N_EDGES) {
        int pos = atomicAdd(&cursor[ei[N_EDGES + i]], 1);
        perm[pos] = i;
    }
    if (i < N_NODES) {
        int pos = atomicAdd(&bcur[batch_ix[i]], 1);
        nperm[pos] = i;
    }
}

// ---------------- weight conversion (fp32 -> bf16)
__global__ void k_wconv(const float* __restrict__ w1, const float* __restrict__ w2,
                        const float* __restrict__ w3, const float* __restrict__ ec1,
                        const float* __restrict__ eew, const float* __restrict__ new_,
                        unsigned short* __restrict__ o1, unsigned short* __restrict__ o2,
                        unsigned short* __restrict__ o3, unsigned short* __restrict__ o4,
                        unsigned short* __restrict__ o5, unsigned short* __restrict__ o6) {
    int i = blockIdx.x * 256 + threadIdx.x;
    if (i < 256 * 416) o1[i] = f2bf(w1[i]);
    if (i < 128 * 256) o2[i] = f2bf(w2[i]);
    if (i < 128 * 288) {
        int r = i / 288, c = i - r * 288;
        o3[i] = (c < 272) ? f2bf(w3[r * 272 + c]) : (unsigned short)0;
    }
    if (i < 64 * 128) o4[i] = f2bf(ec1[i]);
    if (i < 128 * 64) o5[i] = f2bf(eew[i]);
    if (i < 128 * 256) o6[i] = f2bf(new_[i]);
}

// ---------------- node encoder (MFMA): relu(x @ ne_w.T + ne_b) -> (2048,128) fp32
__global__ __launch_bounds__(256) void k_node_enc(const float* __restrict__ x,
                                                  const unsigned short* __restrict__ wb,
                                                  const float* __restrict__ b,
                                                  float* __restrict__ out) {
    __shared__ __attribute__((aligned(16))) unsigned short xs2[64 * 264];
    const int tid = threadIdx.x;
    const int n0 = blockIdx.x * 64;
    {
        int row = tid >> 2, qq = tid & 3;
        const float* rp = x + (size_t)(n0 + row) * 256 + qq * 64;
        unsigned short* dp = &xs2[row * 264 + qq * 64];
#pragma unroll
        for (int j = 0; j < 4; j++) {
            float4 f0 = *(const float4*)(rp + j * 16 + 0);
            float4 f1 = *(const float4*)(rp + j * 16 + 4);
            float4 f2 = *(const float4*)(rp + j * 16 + 8);
            float4 f3 = *(const float4*)(rp + j * 16 + 12);
            s16x8 lo, hi;
            lo[0] = (short)f2bf(f0.x); lo[1] = (short)f2bf(f0.y); lo[2] = (short)f2bf(f0.z); lo[3] = (short)f2bf(f0.w);
            lo[4] = (short)f2bf(f1.x); lo[5] = (short)f2bf(f1.y); lo[6] = (short)f2bf(f1.z); lo[7] = (short)f2bf(f1.w);
            hi[0] = (short)f2bf(f2.x); hi[1] = (short)f2bf(f2.y); hi[2] = (short)f2bf(f2.z); hi[3] = (short)f2bf(f2.w);
            hi[4] = (short)f2bf(f3.x); hi[5] = (short)f2bf(f3.y); hi[6] = (short)f2bf(f3.z); hi[7] = (short)f2bf(f3.w);
            *(s16x8*)(dp + j * 16) = lo;
            *(s16x8*)(dp + j * 16 + 8) = hi;
        }
    }
    __syncthreads();
    const int lane = tid & 63;
    const int wn = tid >> 6;
    const int lr = lane & 15;
    const int lk = lane >> 4;
    const f32x4 z4 = {0.f, 0.f, 0.f, 0.f};
    f32x4 acc[4][2];
#pragma unroll
    for (int mt = 0; mt < 4; mt++)
#pragma unroll
        for (int nt = 0; nt < 2; nt++) acc[mt][nt] = z4;
#pragma unroll
    for (int kc = 0; kc < 8; kc++) {
        s16x8 a0 = *(const s16x8*)&xs2[(0 + lr) * 264 + kc * 32 + lk * 8];
        s16x8 a1 = *(const s16x8*)&xs2[(16 + lr) * 264 + kc * 32 + lk * 8];
        s16x8 a2 = *(const s16x8*)&xs2[(32 + lr) * 264 + kc * 32 + lk * 8];
        s16x8 a3 = *(const s16x8*)&xs2[(48 + lr) * 264 + kc * 32 + lk * 8];
#pragma unroll
        for (int nt = 0; nt < 2; nt++) {
            int nn = wn * 32 + nt * 16 + lr;
            s16x8 bf = *(const s16x8*)&wb[(size_t)nn * 256 + kc * 32 + lk * 8];
            acc[0][nt] = __builtin_amdgcn_mfma_f32_16x16x32_bf16(a0, bf, acc[0][nt], 0, 0, 0);
            acc[1][nt] = __builtin_amdgcn_mfma_f32_16x16x32_bf16(a1, bf, acc[1][nt], 0, 0, 0);
            acc[2][nt] = __builtin_amdgcn_mfma_f32_16x16x32_bf16(a2, bf, acc[2][nt], 0, 0, 0);
            acc[3][nt] = __builtin_amdgcn_mfma_f32_16x16x32_bf16(a3, bf, acc[3][nt], 0, 0, 0);
        }
    }
#pragma unroll
    for (int nt = 0; nt < 2; nt++) {
        int nn = wn * 32 + nt * 16 + lr;
        float bias = b[nn];
#pragma unroll
        for (int mt = 0; mt < 4; mt++)
#pragma unroll
            for (int r = 0; r < 4; r++) {
                int m = mt * 16 + lk * 4 + r;
                out[(size_t)(n0 + m) * 128 + nn] = fmaxf(acc[mt][nt][r] + bias, 0.f);
            }
    }
}

// ---------------- edge encoder (MFMA, writes ef in SORTED slot order)
__global__ __launch_bounds__(256) void k_edge_enc(const float* __restrict__ ea,
                                                  const unsigned short* __restrict__ wb,
                                                  const float* __restrict__ b,
                                                  const int* __restrict__ perm,
                                                  unsigned short* __restrict__ ef) {
    __shared__ __attribute__((aligned(16))) unsigned short eas[64 * 72];
    __shared__ int ep[64];
    const int tid = threadIdx.x;
    const int e0 = blockIdx.x * 64;
    if (tid < 64) ep[tid] = perm[e0 + tid];
    __syncthreads();
    {
        int row = tid >> 2, qq = tid & 3;
        const float* rp = ea + (size_t)ep[row] * 64 + qq * 16;
        float4 f0 = *(const float4*)(rp + 0);
        float4 f1 = *(const float4*)(rp + 4);
        float4 f2 = *(const float4*)(rp + 8);
        float4 f3 = *(const float4*)(rp + 12);
        s16x8 lo, hi;
        lo[0] = (short)f2bf(f0.x); lo[1] = (short)f2bf(f0.y); lo[2] = (short)f2bf(f0.z); lo[3] = (short)f2bf(f0.w);
        lo[4] = (short)f2bf(f1.x); lo[5] = (short)f2bf(f1.y); lo[6] = (short)f2bf(f1.z); lo[7] = (short)f2bf(f1.w);
        hi[0] = (short)f2bf(f2.x); hi[1] = (short)f2bf(f2.y); hi[2] = (short)f2bf(f2.z); hi[3] = (short)f2bf(f2.w);
        hi[4] = (short)f2bf(f3.x); hi[5] = (short)f2bf(f3.y); hi[6] = (short)f2bf(f3.z); hi[7] = (short)f2bf(f3.w);
        unsigned short* dp = &eas[row * 72 + qq * 16];
        *(s16x8*)(dp) = lo;
        *(s16x8*)(dp + 8) = hi;
    }
    __syncthreads();
    const int lane = tid & 63;
    const int wn = tid >> 6;
    const int lr = lane & 15;
    const int lk = lane >> 4;
    const f32x4 z4 = {0.f, 0.f, 0.f, 0.f};
    f32x4 acc[4][2];
#pragma unroll
    for (int mt = 0; mt < 4; mt++)
#pragma unroll
        for (int nt = 0; nt < 2; nt++) acc[mt][nt] = z4;
#pragma unroll
    for (int kc = 0; kc < 2; kc++) {
        s16x8 a0 = *(const s16x8*)&eas[(0 + lr) * 72 + kc * 32 + lk * 8];
        s16x8 a1 = *(const s16x8*)&eas[(16 + lr) * 72 + kc * 32 + lk * 8];
        s16x8 a2 = *(const s16x8*)&eas[(32 + lr) * 72 + kc * 32 + lk * 8];
        s16x8 a3 = *(const s16x8*)&eas[(48 + lr) * 72 + kc * 32 + lk * 8];
#pragma unroll
        for (int nt = 0; nt < 2; nt++) {
            int nn = wn * 32 + nt * 16 + lr;
            s16x8 bf = *(const s16x8*)&wb[(size_t)nn * 64 + kc * 32 + lk * 8];
            acc[0][nt] = __builtin_amdgcn_mfma_f32_16x16x32_bf16(a0, bf, acc[0][nt], 0, 0, 0);
            acc[1][nt] = __builtin_amdgcn_mfma_f32_16x16x32_bf16(a1, bf, acc[1][nt], 0, 0, 0);
            acc[2][nt] = __builtin_amdgcn_mfma_f32_16x16x32_bf16(a2, bf, acc[2][nt], 0, 0, 0);
            acc[3][nt] = __builtin_amdgcn_mfma_f32_16x16x32_bf16(a3, bf, acc[3][nt], 0, 0, 0);
        }
    }
#pragma unroll
    for (int nt = 0; nt < 2; nt++) {
        int nn = wn * 32 + nt * 16 + lr;
        float bias = b[nn];
#pragma unroll
        for (int mt = 0; mt < 4; mt++)
#pragma unroll
            for (int r = 0; r < 4; r++) {
                int m = mt * 16 + lk * 4 + r;
                ef[(size_t)(e0 + m) * 128 + nn] = f2bf(fmaxf(acc[mt][nt][r] + bias, 0.f));
            }
    }
}

// ---------------- queries/values: einsum('oc,bcp->bop') + bias
__global__ __launch_bounds__(256) void k_qv(const float* __restrict__ fm,
                                            const float* __restrict__ qw, const float* __restrict__ qb,
                                            const float* __restrict__ vw, const float* __restrict__ vb,
                                            float* __restrict__ q, float* __restrict__ v) {
    __shared__ float fs[32][256];
    const int b = blockIdx.x >> 4;
    const int pt = blockIdx.x & 15;
    for (int i = threadIdx.x; i < 32 * 256; i += 256) {
        int c = i >> 8, p = i & 255;
        fs[c][p] = fm[(size_t)b * 32 * PPIX + (size_t)c * PPIX + pt * 256 + p];
    }
    __syncthreads();
    const int p = threadIdx.x;
    for (int o = 0; o < 16; o++) {
        float qa = qb[o], va = vb[o];
#pragma unroll
        for (int c = 0; c < 32; c++) {
            float f = fs[c][p];
            qa += qw[o * 32 + c] * f;
            va += vw[o * 32 + c] * f;
        }
        size_t oidx = ((size_t)b * 16 + o) * PPIX + pt * 256 + p;
        q[oidx] = qa;
        v[oidx] = va;
    }
}

// ---------------- attention: 4 nodes/block (same batch), TWO-PASS softmax.
__global__ __launch_bounds__(256) void k_attn(const float* __restrict__ nf,
                                              const float* __restrict__ qbuf,
                                              const float* __restrict__ vbuf,
                                              const float* __restrict__ key_w,
                                              const float* __restrict__ key_b,
                                              const int* __restrict__ nperm,
                                              const int* __restrict__ boff,
                                              const int* __restrict__ bcnt,
                                              unsigned short* __restrict__ nf_bf,
                                              float* __restrict__ nxt) {
    const int b = blockIdx.x >> 9;       // grid = 4 * 512
    const int chunk = blockIdx.x & 511;
    const int cnt = bcnt[b];
    if (chunk * 4 >= cnt) return;
    const int base = boff[b] + chunk * 4;
    const int nvalid = min(4, cnt - chunk * 4);
    const int t = threadIdx.x;

    __shared__ int nid[4];
    __shared__ float xs[4][128];
    __shared__ float ks[4][16];
    __shared__ float redm[4][4];       // [wave][node] partial max
    __shared__ float pbuf[4][4][17];   // [wave][node][wsum, vacc16]

    if (t < 4) nid[t] = nperm[base + ((t < nvalid) ? t : 0)];
    __syncthreads();
    for (int i2 = t; i2 < 4 * 128; i2 += 256) {
        int i = i2 >> 7, d = i2 & 127;
        xs[i][d] = nf[(size_t)nid[i] * 128 + d];
        if (i < nvalid) nxt[(size_t)nid[i] * 128 + d] = 0.f;   // zero next accumulator
    }
    __syncthreads();
    if (t < 64) {
        int i = t >> 4, a = t & 15;
        const float* wr = key_w + a * 128;
        float acc = key_b[a];
#pragma unroll 8
        for (int c = 0; c < 128; c++) acc += xs[i][c] * wr[c];
        ks[i][a] = acc;
    }
    __syncthreads();
    float kk[4][16];
#pragma unroll
    for (int i = 0; i < 4; i++)
#pragma unroll
        for (int a = 0; a < 16; a++) kk[i][a] = ks[i][a];

    const float* q = qbuf + (size_t)b * 16 * PPIX;
    const float* v = vbuf + (size_t)b * 16 * PPIX;

    // ---- pass A: scores + max
    float s[4][16];
    float m[4] = {-3e38f, -3e38f, -3e38f, -3e38f};
#pragma unroll
    for (int ch = 0; ch < 16; ch++) {
        int p = ch * 256 + t;
        float qv[16];
#pragma unroll
        for (int a = 0; a < 16; a++) qv[a] = q[a * PPIX + p];
#pragma unroll
        for (int i = 0; i < 4; i++) {
            float acc = 0.f;
#pragma unroll
            for (int a = 0; a < 16; a++) acc += kk[i][a] * qv[a];
            s[i][ch] = acc;
            m[i] = fmaxf(m[i], acc);
        }
    }
#pragma unroll
    for (int off = 1; off < 64; off <<= 1)
#pragma unroll
        for (int i = 0; i < 4; i++) m[i] = fmaxf(m[i], __shfl_xor(m[i], off));
    const int wv = t >> 6;
    if ((t & 63) == 0) {
#pragma unroll
        for (int i = 0; i < 4; i++) redm[wv][i] = m[i];
    }
    __syncthreads();
    float mf[4];
#pragma unroll
    for (int i = 0; i < 4; i++)
        mf[i] = fmaxf(fmaxf(redm[0][i], redm[1][i]), fmaxf(redm[2][i], redm[3][i]));

    // ---- pass B: exp + weighted V
    float wsm[4] = {0.f, 0.f, 0.f, 0.f};
    float vacc[4][16];
#pragma unroll
    for (int i = 0; i < 4; i++)
#pragma unroll
        for (int a = 0; a < 16; a++) vacc[i][a] = 0.f;
#pragma unroll
    for (int ch = 0; ch < 16; ch++) {
        int p = ch * 256 + t;
        float vv[16];
#pragma unroll
        for (int a = 0; a < 16; a++) vv[a] = v[a * PPIX + p];
#pragma unroll
        for (int i = 0; i < 4; i++) {
            float w = __expf(s[i][ch] - mf[i]);
            wsm[i] += w;
#pragma unroll
            for (int a = 0; a < 16; a++) vacc[i][a] += w * vv[a];
        }
    }
#pragma unroll
    for (int off = 1; off < 64; off <<= 1)
#pragma unroll
        for (int i = 0; i < 4; i++) {
            wsm[i] += __shfl_xor(wsm[i], off);
#pragma unroll
            for (int a = 0; a < 16; a++) vacc[i][a] += __shfl_xor(vacc[i][a], off);
        }
    if ((t & 63) == 0) {
#pragma unroll
        for (int i = 0; i < 4; i++) {
            pbuf[wv][i][0] = wsm[i];
#pragma unroll
            for (int a = 0; a < 16; a++) pbuf[wv][i][1 + a] = vacc[i][a];
        }
    }
    __syncthreads();
    if (t < 64) {
        int i = t >> 4, a = t & 15;
        float den = pbuf[0][i][0] + pbuf[1][i][0] + pbuf[2][i][0] + pbuf[3][i][0];
        float num = pbuf[0][i][1 + a] + pbuf[1][i][1 + a] + pbuf[2][i][1 + a] + pbuf[3][i][1 + a];
        if (i < nvalid) nf_bf[(size_t)nid[i] * 144 + 128 + a] = f2bf(num / den);
    }
    // pack x part
    for (int i2 = t; i2 < 4 * 128; i2 += 256) {
        int i = i2 >> 7, d = i2 & 127;
        if (i < nvalid) nf_bf[(size_t)nid[i] * 144 + d] = f2bf(xs[i][d]);
    }
}

// ---------------- fused 3-layer edge MLP + segment-reduced message scatter
// tile = 128 SORTED edges, 512 threads (8 waves). Wave = PURE N-SLICE: every
// B-fragment is loaded exactly once per block (L2 weight traffic 704->176 MB
// per dispatch; round-6 model showed k_mlp is L2-weight-BW bound at 56 B/cyc/CU).
// Each wave computes all 8 m-subtiles for its column slice.
// LDS catA = 128x424x2 = 108.5 KB -> 1 block/CU, 8 waves (2/SIMD).
__global__ __launch_bounds__(512, 2) void k_mlp(const unsigned short* __restrict__ nf_bf,
                                                unsigned short* __restrict__ ef_buf,
                                                const unsigned short* __restrict__ w1b,
                                                const unsigned short* __restrict__ w2b,
                                                const unsigned short* __restrict__ w3b,
                                                const float* __restrict__ me_b1,
                                                const float* __restrict__ me_b2,
                                                const float* __restrict__ mn_b,
                                                const int* __restrict__ ei,
                                                const int* __restrict__ perm,
                                                float* __restrict__ node_acc) {
    __shared__ __attribute__((aligned(16))) unsigned short catA[128 * 424]; // [x_i 0:144 | x_j 144:288 | ef 288:416 | pad]
    __shared__ int tgt_s[128];
    __shared__ int src_s[128];
    const int tid = threadIdx.x;
    const int e0 = blockIdx.x * 128;
    const int* srcI = ei;
    const int* tgtI = ei + N_EDGES;
    if (tid < 128) {
        int eg = perm[e0 + tid];
        tgt_s[tid] = tgtI[eg];
        src_s[tid] = srcI[eg];
    }
    __syncthreads();
    // gather staging: 52 x 16B chunks per edge, 128 edges (13 iters/thread)
    for (int c = tid; c < 128 * 52; c += 512) {
        int e = c / 52;
        int r = c - e * 52;
        const unsigned short* sp;
        int dcol;
        if (r < 18)      { sp = nf_bf + (size_t)tgt_s[e] * 144 + r * 8;        dcol = r * 8; }
        else if (r < 36) { sp = nf_bf + (size_t)src_s[e] * 144 + (r - 18) * 8; dcol = 144 + (r - 18) * 8; }
        else             { sp = ef_buf + (size_t)(e0 + e) * 128 + (r - 36) * 8; dcol = 288 + (r - 36) * 8; }
        *(s16x8*)&catA[e * 424 + dcol] = *(const s16x8*)sp;
    }
    __syncthreads();

    const int lane = tid & 63;
    const int wn = tid >> 6;        // 0..7 : pure n-slice owner
    const int lr = lane & 15;
    const int lk = lane >> 4;
    const f32x4 z4 = {0.f, 0.f, 0.f, 0.f};

    // ---- layer 1: (128 x 416) @ (416 x 256); wave: all 128 rows, cols wn*32..+32
    f32x4 acc[8][2];
#pragma unroll
    for (int mt = 0; mt < 8; mt++)
#pragma unroll
        for (int nt = 0; nt < 2; nt++) acc[mt][nt] = z4;
#pragma unroll 2
    for (int kc = 0; kc < 13; kc++) {
        s16x8 a0 = *(const s16x8*)&catA[(0 * 16 + lr) * 424 + kc * 32 + lk * 8];
        s16x8 a1 = *(const s16x8*)&catA[(1 * 16 + lr) * 424 + kc * 32 + lk * 8];
        s16x8 a2 = *(const s16x8*)&catA[(2 * 16 + lr) * 424 + kc * 32 + lk * 8];
        s16x8 a3 = *(const s16x8*)&catA[(3 * 16 + lr) * 424 + kc * 32 + lk * 8];
        s16x8 a4 = *(const s16x8*)&catA[(4 * 16 + lr) * 424 + kc * 32 + lk * 8];
        s16x8 a5 = *(const s16x8*)&catA[(5 * 16 + lr) * 424 + kc * 32 + lk * 8];
        s16x8 a6 = *(const s16x8*)&catA[(6 * 16 + lr) * 424 + kc * 32 + lk * 8];
        s16x8 a7 = *(const s16x8*)&catA[(7 * 16 + lr) * 424 + kc * 32 + lk * 8];
#pragma unroll
        for (int nt = 0; nt < 2; nt++) {
            int nn = wn * 32 + nt * 16 + lr;
            s16x8 b = *(const s16x8*)&w1b[(size_t)nn * 416 + kc * 32 + lk * 8];
            acc[0][nt] = __builtin_amdgcn_mfma_f32_16x16x32_bf16(a0, b, acc[0][nt], 0, 0, 0);
            acc[1][nt] = __builtin_amdgcn_mfma_f32_16x16x32_bf16(a1, b, acc[1][nt], 0, 0, 0);
            acc[2][nt] = __builtin_amdgcn_mfma_f32_16x16x32_bf16(a2, b, acc[2][nt], 0, 0, 0);
            acc[3][nt] = __builtin_amdgcn_mfma_f32_16x16x32_bf16(a3, b, acc[3][nt], 0, 0, 0);
            acc[4][nt] = __builtin_amdgcn_mfma_f32_16x16x32_bf16(a4, b, acc[4][nt], 0, 0, 0);
            acc[5][nt] = __builtin_amdgcn_mfma_f32_16x16x32_bf16(a5, b, acc[5][nt], 0, 0, 0);
            acc[6][nt] = __builtin_amdgcn_mfma_f32_16x16x32_bf16(a6, b, acc[6][nt], 0, 0, 0);
            acc[7][nt] = __builtin_amdgcn_mfma_f32_16x16x32_bf16(a7, b, acc[7][nt], 0, 0, 0);
        }
    }
    __syncthreads();   // all L1 reads of catA done -> cols 144:416 now dead
#pragma unroll
    for (int nt = 0; nt < 2; nt++) {
        int nn = wn * 32 + nt * 16 + lr;
        float bias = me_b1[nn];
#pragma unroll
        for (int mt = 0; mt < 8; mt++)
#pragma unroll
            for (int r = 0; r < 4; r++) {
                int m = mt * 16 + lk * 4 + r;
                catA[m * 424 + 144 + nn] = f2bf(fmaxf(acc[mt][nt][r] + bias, 0.f));
            }
    }
    __syncthreads();

    // ---- layer 2: (128 x 256) @ (256 x 128); wave cols wn*16..+16
    f32x4 acc2[8];
#pragma unroll
    for (int mt = 0; mt < 8; mt++) acc2[mt] = z4;
    const int nn2 = wn * 16 + lr;
#pragma unroll 2
    for (int kc = 0; kc < 8; kc++) {
        s16x8 a0 = *(const s16x8*)&catA[(0 * 16 + lr) * 424 + 144 + kc * 32 + lk * 8];
        s16x8 a1 = *(const s16x8*)&catA[(1 * 16 + lr) * 424 + 144 + kc * 32 + lk * 8];
        s16x8 a2 = *(const s16x8*)&catA[(2 * 16 + lr) * 424 + 144 + kc * 32 + lk * 8];
        s16x8 a3 = *(const s16x8*)&catA[(3 * 16 + lr) * 424 + 144 + kc * 32 + lk * 8];
        s16x8 a4 = *(const s16x8*)&catA[(4 * 16 + lr) * 424 + 144 + kc * 32 + lk * 8];
        s16x8 a5 = *(const s16x8*)&catA[(5 * 16 + lr) * 424 + 144 + kc * 32 + lk * 8];
        s16x8 a6 = *(const s16x8*)&catA[(6 * 16 + lr) * 424 + 144 + kc * 32 + lk * 8];
        s16x8 a7 = *(const s16x8*)&catA[(7 * 16 + lr) * 424 + 144 + kc * 32 + lk * 8];
        s16x8 b = *(const s16x8*)&w2b[(size_t)nn2 * 256 + kc * 32 + lk * 8];
        acc2[0] = __builtin_amdgcn_mfma_f32_16x16x32_bf16(a0, b, acc2[0], 0, 0, 0);
        acc2[1] = __builtin_amdgcn_mfma_f32_16x16x32_bf16(a1, b, acc2[1], 0, 0, 0);
        acc2[2] = __builtin_amdgcn_mfma_f32_16x16x32_bf16(a2, b, acc2[2], 0, 0, 0);
        acc2[3] = __builtin_amdgcn_mfma_f32_16x16x32_bf16(a3, b, acc2[3], 0, 0, 0);
        acc2[4] = __builtin_amdgcn_mfma_f32_16x16x32_bf16(a4, b, acc2[4], 0, 0, 0);
        acc2[5] = __builtin_amdgcn_mfma_f32_16x16x32_bf16(a5, b, acc2[5], 0, 0, 0);
        acc2[6] = __builtin_amdgcn_mfma_f32_16x16x32_bf16(a6, b, acc2[6], 0, 0, 0);
        acc2[7] = __builtin_amdgcn_mfma_f32_16x16x32_bf16(a7, b, acc2[7], 0, 0, 0);
    }
    __syncthreads();   // all L2 reads of out1 overlay done
#pragma unroll
    for (int mt = 0; mt < 8; mt++)
#pragma unroll
        for (int r = 0; r < 4; r++) {
            int m = mt * 16 + lk * 4 + r;
            catA[m * 424 + 144 + nn2] = f2bf(fmaxf(acc2[mt][r] + me_b2[nn2], 0.f));
        }
    __syncthreads();

    // ---- layer 3: (128 x 288) @ (288 x 128). cols 272:288 junk x zero-weights.
    f32x4 acc3[8];
#pragma unroll
    for (int mt = 0; mt < 8; mt++) acc3[mt] = z4;
#pragma unroll 2
    for (int kc = 0; kc < 9; kc++) {
        s16x8 a0 = *(const s16x8*)&catA[(0 * 16 + lr) * 424 + kc * 32 + lk * 8];
        s16x8 a1 = *(const s16x8*)&catA[(1 * 16 + lr) * 424 + kc * 32 + lk * 8];
        s16x8 a2 = *(const s16x8*)&catA[(2 * 16 + lr) * 424 + kc * 32 + lk * 8];
        s16x8 a3 = *(const s16x8*)&catA[(3 * 16 + lr) * 424 + kc * 32 + lk * 8];
        s16x8 a4 = *(const s16x8*)&catA[(4 * 16 + lr) * 424 + kc * 32 + lk * 8];
        s16x8 a5 = *(const s16x8*)&catA[(5 * 16 + lr) * 424 + kc * 32 + lk * 8];
        s16x8 a6 = *(const s16x8*)&catA[(6 * 16 + lr) * 424 + kc * 32 + lk * 8];
        s16x8 a7 = *(const s16x8*)&catA[(7 * 16 + lr) * 424 + kc * 32 + lk * 8];
        s16x8 b = *(const s16x8*)&w3b[(size_t)nn2 * 288 + kc * 32 + lk * 8];
        acc3[0] = __builtin_amdgcn_mfma_f32_16x16x32_bf16(a0, b, acc3[0], 0, 0, 0);
        acc3[1] = __builtin_amdgcn_mfma_f32_16x16x32_bf16(a1, b, acc3[1], 0, 0, 0);
        acc3[2] = __builtin_amdgcn_mfma_f32_16x16x32_bf16(a2, b, acc3[2], 0, 0, 0);
        acc3[3] = __builtin_amdgcn_mfma_f32_16x16x32_bf16(a3, b, acc3[3], 0, 0, 0);
        acc3[4] = __builtin_amdgcn_mfma_f32_16x16x32_bf16(a4, b, acc3[4], 0, 0, 0);
        acc3[5] = __builtin_amdgcn_mfma_f32_16x16x32_bf16(a5, b, acc3[5], 0, 0, 0);
        acc3[6] = __builtin_amdgcn_mfma_f32_16x16x32_bf16(a6, b, acc3[6], 0, 0, 0);
        acc3[7] = __builtin_amdgcn_mfma_f32_16x16x32_bf16(a7, b, acc3[7], 0, 0, 0);
    }
    __syncthreads();   // all L3 reads of catA done -> overlay free for msg (fp32)
#pragma unroll
    for (int mt = 0; mt < 8; mt++)
#pragma unroll
        for (int r = 0; r < 4; r++) {
            int m = mt * 16 + lk * 4 + r;
            *(float*)&catA[m * 424 + 144 + nn2 * 2] = fmaxf(acc3[mt][r] + mn_b[nn2], 0.f);
        }
    __syncthreads();
    // segment-reduce: sorted tgt -> runs; 512 threads = 128 cols x 4 row-chunks of 32
    {
        const int c = tid & 127;
        const int r0 = (tid >> 7) * 32;
        float run = *(const float*)&catA[r0 * 424 + 144 + c * 2];
        int prev = tgt_s[r0];
        for (int r = r0 + 1; r < r0 + 32; r++) {
            int tg = tgt_s[r];
            float val = *(const float*)&catA[r * 424 + 144 + c * 2];
            if (tg != prev) {
                atomicAdd(&node_acc[(size_t)prev * 128 + c], run);
                run = val;
                prev = tg;
            } else {
                run += val;
            }
        }
        atomicAdd(&node_acc[(size_t)prev * 128 + c], run);
    }
    // deferred global ef write (from acc2 regs; no barrier after -> no drain stall)
    {
        float bias = me_b2[nn2];
#pragma unroll
        for (int mt = 0; mt < 8; mt++)
#pragma unroll
            for (int r = 0; r < 4; r++) {
                int m = mt * 16 + lk * 4 + r;
                ef_buf[(size_t)(e0 + m) * 128 + nn2] = f2bf(fmaxf(acc2[mt][r] + bias, 0.f));
            }
    }
}

// ---------------- edge head (MFMA): pe + fp32 edge_features output (unsorts via perm)
__global__ __launch_bounds__(256) void k_edge_head(const unsigned short* __restrict__ ef,
                                                   const unsigned short* __restrict__ w1b,
                                                   const float* __restrict__ b1,
                                                   const float* __restrict__ w2,
                                                   const float* __restrict__ b2,
                                                   const int* __restrict__ perm,
                                                   float* __restrict__ pe,
                                                   float* __restrict__ ef_out) {
    __shared__ __attribute__((aligned(16))) unsigned short efs[32][136];
    __shared__ float h_s[32][68];
    __shared__ int ep_s[32];
    const int tid = threadIdx.x;
    const int e0 = blockIdx.x * 32;
    if (tid < 32) ep_s[tid] = perm[e0 + tid];
    __syncthreads();
    // stage 32x128 bf16 tile + write fp32 ef_out (at original edge index)
    for (int c = tid; c < 32 * 16; c += 256) {
        int e = c >> 4, r = c & 15;
        s16x8 v = *(const s16x8*)&ef[(size_t)(e0 + e) * 128 + r * 8];
        *(s16x8*)&efs[e][r * 8] = v;
        float4 lo, hi;
        lo.x = bf2f((unsigned short)v[0]); lo.y = bf2f((unsigned short)v[1]);
        lo.z = bf2f((unsigned short)v[2]); lo.w = bf2f((unsigned short)v[3]);
        hi.x = bf2f((unsigned short)v[4]); hi.y = bf2f((unsigned short)v[5]);
        hi.z = bf2f((unsigned short)v[6]); hi.w = bf2f((unsigned short)v[7]);
        size_t ob = (size_t)ep_s[e] * 128 + r * 8;
        *(float4*)&ef_out[ob] = lo;
        *(float4*)&ef_out[ob + 4] = hi;
    }
    __syncthreads();
    const int lane = tid & 63;
    const int wid = tid >> 6;   // owns h block wid*16
    const int lr = lane & 15;
    const int lk = lane >> 4;
    const f32x4 z4 = {0.f, 0.f, 0.f, 0.f};
    f32x4 acc0 = z4, acc1 = z4;
    for (int kc = 0; kc < 4; kc++) {
        s16x8 a0 = *(const s16x8*)&efs[lr][kc * 32 + lk * 8];
        s16x8 a1 = *(const s16x8*)&efs[16 + lr][kc * 32 + lk * 8];
        s16x8 b = *(const s16x8*)&w1b[(size_t)(wid * 16 + lr) * 128 + kc * 32 + lk * 8];
        acc0 = __builtin_amdgcn_mfma_f32_16x16x32_bf16(a0, b, acc0, 0, 0, 0);
        acc1 = __builtin_amdgcn_mfma_f32_16x16x32_bf16(a1, b, acc1, 0, 0, 0);
    }
    {
        int h = wid * 16 + lr;
        float bias = b1[h];
#pragma unroll
        for (int r = 0; r < 4; r++) {
            h_s[lk * 4 + r][h]      = fmaxf(acc0[r] + bias, 0.f);
            h_s[16 + lk * 4 + r][h] = fmaxf(acc1[r] + bias, 0.f);
        }
    }
    __syncthreads();
    if (tid < 32) {
        float a = b2[0];
#pragma unroll 8
        for (int h = 0; h < 64; h++) a += w2[h] * h_s[tid][h];
        pe[ep_s[tid]] = a;
    }
}

// ---------------- fused node heads: pn, pc, nf_out. One wave per node.
__global__ __launch_bounds__(64) void k_node_heads(const float* __restrict__ nf,
                                                   const float* __restrict__ nc_w1, const float* __restrict__ nc_b1,
                                                   const float* __restrict__ nc_w2, const float* __restrict__ nc_b2,
                                                   const float* __restrict__ cl_w1, const float* __restrict__ cl_b1,
                                                   const float* __restrict__ cl_w2, const float* __restrict__ cl_b2,
                                                   float* __restrict__ pn, float* __restrict__ pc,
                                                   float* __restrict__ nf_out) {
    __shared__ float xs[128];
    __shared__ float hr2[64];
    const int n = blockIdx.x;
    const int t = threadIdx.x;
    float2 xv = *(const float2*)&nf[(size_t)n * 128 + t * 2];
    xs[t * 2] = xv.x;
    xs[t * 2 + 1] = xv.y;
    *(float2*)&nf_out[(size_t)n * 128 + t * 2] = xv;
    __syncthreads();
    float a1 = nc_b1[t], a2 = cl_b1[t];
#pragma unroll 8
    for (int d4 = 0; d4 < 32; d4++) {
        float4 w1v = *(const float4*)&nc_w1[(size_t)t * 128 + d4 * 4];
        float4 w2v = *(const float4*)&cl_w1[(size_t)t * 128 + d4 * 4];
        float x0 = xs[d4 * 4], x1 = xs[d4 * 4 + 1], x2 = xs[d4 * 4 + 2], x3 = xs[d4 * 4 + 3];
        a1 += x0 * w1v.x + x1 * w1v.y + x2 * w1v.z + x3 * w1v.w;
        a2 += x0 * w2v.x + x1 * w2v.y + x2 * w2v.z + x3 * w2v.w;
    }
    float h1 = fmaxf(a1, 0.f);
    hr2[t] = fmaxf(a2, 0.f);
    float p = nc_w2[t] * h1;
#pragma unroll
    for (int off = 32; off > 0; off >>= 1) p += __shfl_down(p, off);
    if (t == 0) pn[n] = p + nc_b2[0];
    __syncthreads();
    if (t < 17) {
        float a = cl_b2[t];
#pragma unroll 8
        for (int h = 0; h < 64; h++) a += cl_w2[t * 64 + h] * hr2[h];
        pc[(size_t)n * 17 + t] = a;
    }
}

extern "C" void kernel_launch(void* const* d_in, const int* in_sizes, int n_in,
                              void* d_out, int out_size, void* d_ws, size_t ws_size,
                              hipStream_t stream) {
    const float* x         = (const float*)d_in[0];
    const float* edge_attr = (const float*)d_in[1];
    const int*   edge_idx  = (const int*)d_in[2];
    const float* fmaps     = (const float*)d_in[3];
    const int*   batch_ix  = (const int*)d_in[4];
    const float* ne_w  = (const float*)d_in[5];
    const float* ne_b  = (const float*)d_in[6];
    const float* ee_w  = (const float*)d_in[7];
    const float* ee_b  = (const float*)d_in[8];
    const float* me_w1 = (const float*)d_in[9];
    const float* me_b1 = (const float*)d_in[10];
    const float* me_w2 = (const float*)d_in[11];
    const float* me_b2 = (const float*)d_in[12];
    const float* mn_w  = (const float*)d_in[13];
    const float* mn_b  = (const float*)d_in[14];
    const float* key_w = (const float*)d_in[15];
    const float* key_b = (const float*)d_in[16];
    const float* q_w   = (const float*)d_in[17];
    const float* q_b   = (const float*)d_in[18];
    const float* v_w   = (const float*)d_in[19];
    const float* v_b   = (const float*)d_in[20];
    const float* ec_w1 = (const float*)d_in[21];
    const float* ec_b1 = (const float*)d_in[22];
    const float* ec_w2 = (const float*)d_in[23];
    const float* ec_b2 = (const float*)d_in[24];
    const float* nc_w1 = (const float*)d_in[25];
    const float* nc_b1 = (const float*)d_in[26];
    const float* nc_w2 = (const float*)d_in[27];
    const float* nc_b2 = (const float*)d_in[28];
    const float* cl_w1 = (const float*)d_in[29];
    const float* cl_b1 = (const float*)d_in[30];
    const float* cl_w2 = (const float*)d_in[31];
    const float* cl_b2 = (const float*)d_in[32];

    char* wsp = (char*)d_ws;
    size_t off = 0;
    auto alloc = [&](size_t bytes) -> void* {
        void* p = wsp + off;
        off += (bytes + 255) & ~(size_t)255;
        return p;
    };
    float* q_buf = (float*)alloc((size_t)BATCH * 16 * PPIX * sizeof(float));
    float* v_buf = (float*)alloc((size_t)BATCH * 16 * PPIX * sizeof(float));
    float* nfA   = (float*)alloc((size_t)N_NODES * 128 * sizeof(float));
    float* nfB   = (float*)alloc((size_t)N_NODES * 128 * sizeof(float));
    unsigned short* nf_bf  = (unsigned short*)alloc((size_t)N_NODES * 144 * 2);
    unsigned short* ef_buf = (unsigned short*)alloc((size_t)N_EDGES * 128 * 2);
    unsigned short* w1b = (unsigned short*)alloc(256 * 416 * 2);
    unsigned short* w2b = (unsigned short*)alloc(128 * 256 * 2);
    unsigned short* w3b = (unsigned short*)alloc(128 * 288 * 2);
    unsigned short* w4b = (unsigned short*)alloc(64 * 128 * 2);
    unsigned short* w5b = (unsigned short*)alloc(128 * 64 * 2);
    unsigned short* w6b = (unsigned short*)alloc(128 * 256 * 2);
    int* hist   = (int*)alloc((2048 + 4) * sizeof(int));   // hist + bcnt (memset together)
    int* bcnt   = hist + 2048;
    int* cursor = (int*)alloc(2048 * sizeof(int));
    int* boff   = (int*)alloc(4 * sizeof(int));
    int* bcur   = (int*)alloc(4 * sizeof(int));
    int* perm   = (int*)alloc((size_t)N_EDGES * sizeof(int));
    int* nperm  = (int*)alloc((size_t)N_NODES * sizeof(int));

    float* pe_out = (float*)d_out;
    float* pn_out = pe_out + N_EDGES;
    float* pc_out = pn_out + N_NODES;
    float* nf_out = pc_out + (size_t)N_NODES * 17;
    float* ef_out = nf_out + (size_t)N_NODES * 128;

    // ---- sort edges by tgt, nodes by batch
    hipMemsetAsync(hist, 0, (2048 + 4) * sizeof(int), stream);
    k_hist<<<N_EDGES / 256, 256, 0, stream>>>(edge_idx, batch_ix, hist, bcnt);
    k_scan<<<1, 256, 0, stream>>>(hist, bcnt, cursor, boff, bcur);
    k_scatter<<<N_EDGES / 256, 256, 0, stream>>>(edge_idx, batch_ix, cursor, bcur, perm, nperm);

    k_wconv<<<416, 256, 0, stream>>>(me_w1, me_w2, mn_w, ec_w1, ee_w, ne_w,
                                     w1b, w2b, w3b, w4b, w5b, w6b);
    k_node_enc<<<N_NODES / 64, 256, 0, stream>>>(x, w6b, ne_b, nfA);
    k_qv<<<64, 256, 0, stream>>>(fmaps, q_w, q_b, v_w, v_b, q_buf, v_buf);
    k_edge_enc<<<N_EDGES / 64, 256, 0, stream>>>(edge_attr, w5b, ee_b, perm, ef_buf);

    float* cur = nfA;
    float* nxt = nfB;
    for (int step = 0; step < STEPS; step++) {
        k_attn<<<BATCH * 512, 256, 0, stream>>>(cur, q_buf, v_buf, key_w, key_b,
                                                nperm, boff, bcnt, nf_bf, nxt);
        k_mlp<<<N_EDGES / 128, 512, 0, stream>>>(nf_bf, ef_buf, w1b, w2b, w3b,
                                                 me_b1, me_b2, mn_b, edge_idx, perm, nxt);
        float* tmp = cur; cur = nxt; nxt = tmp;
    }

    k_edge_head<<<N_EDGES / 32, 256, 0, stream>>>(ef_buf, w4b, ec_b1, ec_w2, ec_b2, perm, pe_out, ef_out);
    k_node_heads<<<N_NODES, 64, 0, stream>>>(cur, nc_w1, nc_b1, nc_w2, nc_b2,
                                             cl_w1, cl_b1, cl_w2, cl_b2, pn_out, pc_out, nf_out);
}